// Round 6
// baseline (318.444 us; speedup 1.0000x reference)
//
#include <hip/hip_runtime.h>

#define LN_EPS 1e-5f

typedef __attribute__((ext_vector_type(8))) short short8;
typedef __attribute__((ext_vector_type(4))) float f32x4;

__device__ __forceinline__ float sigf(float x) { return 1.0f / (1.0f + __expf(-x)); }

__device__ __forceinline__ unsigned short f2bf(float f) {
    unsigned u = __float_as_uint(f);
    return (unsigned short)((u + 0x7fffu + ((u >> 16) & 1u)) >> 16);
}
__device__ __forceinline__ unsigned f2bf2(float lo, float hi) {
    return (unsigned)f2bf(lo) | ((unsigned)f2bf(hi) << 16);
}
__device__ __forceinline__ void bf2f(unsigned u, float& lo, float& hi) {
    lo = __uint_as_float(u << 16);
    hi = __uint_as_float(u & 0xffff0000u);
}
__device__ __forceinline__ void bf8f(uint4 p, float* o) {
    bf2f(p.x, o[0], o[1]); bf2f(p.y, o[2], o[3]);
    bf2f(p.z, o[4], o[5]); bf2f(p.w, o[6], o[7]);
}

// ---- weight prep: f32 [128][128] row-major -> fragment-linear bf16 ----
__global__ __launch_bounds__(256)
void prep_w(const float* __restrict__ lin_w, const float* __restrict__ msg_w1,
            const float* __restrict__ msg_w2, const float* __restrict__ att_w1,
            const float* __restrict__ out_w1, const float* __restrict__ out_w2,
            const float* __restrict__ att_b1, unsigned short* __restrict__ wp,
            float* __restrict__ bias256)
{
    const int idx = blockIdx.x * 256 + threadIdx.x;
    if (idx < 8 * 16384) {
        const int m = idx >> 14, r = idx & 16383;
        const int k = r >> 7, n = r & 127;
        const float* src; int slot; int fnBase = 0;
        switch (m) {
            case 0: src = lin_w;  slot = 0; break;
            case 1: src = msg_w1; slot = 1; break;
            case 2: src = msg_w2; slot = 2; break;
            case 3: src = att_w1; slot = 3; break;
            case 4: src = att_w1 + 128 * 128; slot = 3; fnBase = 8; break;
            case 5: src = out_w1; slot = 5; break;
            default: src = out_w2; slot = 6; break;
        }
        const float v = src[k * 128 + n];
        const int fn = fnBase + (n >> 4);
        const int fk = k >> 5, kb = (k >> 3) & 3, j = k & 7;
        const size_t dst = (size_t)slot * 16384 + ((size_t)((fn * 4 + fk) * 64 + (n & 15) + 16 * kb)) * 8 + j;
        wp[dst] = f2bf(v);
    } else if (idx < 8 * 16384 + 256) {
        const int t = idx - 8 * 16384;
        bias256[t] = (t < 128) ? att_b1[t] : 0.f;
    }
}

// ---- bf16 MFMA GEMM: epi(A[N,128] @ W + bias) with flexible destinations ----
// ABF: A bf16.  OBF: 0 = f32 C1; 1 = bf16 C1; 2 = f32 C1 + bf16 copy C2.
// SPLIT (NFN=16 only): fn<8 -> bf16 C1/ld1, fn>=8 -> bf16 C2/ld2 (fn rebased).
// EPI 0: +bias; EPI 2: silu(.+bias) then LN; EPI 3: (.+bias+res) then LN
template<int EPI, int NFN, int ABF, int OBF, int SPLIT>
__global__ __launch_bounds__(256, (NFN == 8 ? 3 : 2))
void gemm_mfma(const void* __restrict__ Av, const unsigned short* __restrict__ Wp,
               const float* __restrict__ bias, const float* __restrict__ lng,
               const float* __restrict__ lnb, const float* __restrict__ res,
               void* __restrict__ C1v, int ld1, void* __restrict__ C2v, int ld2,
               int nrows)
{
    extern __shared__ uint4 lds[];
    uint4* ldsA = lds;            // 1024 packets (frag-linear bf16)
    uint4* ldsB = lds + 1024;     // NFN*256 packets

    const int tid = threadIdx.x;
    const int r0 = blockIdx.x * 64;

    const uint4* Wp4 = (const uint4*)Wp;
#pragma unroll
    for (int i = 0; i < NFN; ++i) ldsB[tid + i * 256] = Wp4[tid + i * 256];

#pragma unroll
    for (int i = 0; i < 4; ++i) {
        const int p = i * 256 + tid;
        const int row = p & 63, kp = p >> 6;
        int gr = r0 + row; if (gr >= nrows) gr = nrows - 1;
        uint4 pk;
        if (ABF) {
            pk = *(const uint4*)((const unsigned short*)Av + (size_t)gr * 128 + kp * 8);
        } else {
            const float* ap = (const float*)Av + (size_t)gr * 128 + kp * 8;
            const float4 f0 = *(const float4*)ap;
            const float4 f1 = *(const float4*)(ap + 4);
            pk.x = f2bf2(f0.x, f0.y); pk.y = f2bf2(f0.z, f0.w);
            pk.z = f2bf2(f1.x, f1.y); pk.w = f2bf2(f1.z, f1.w);
        }
        const int fr = row >> 4, fk = kp >> 2, kb = kp & 3;
        ldsA[(fr * 4 + fk) * 64 + (row & 15) + 16 * kb] = pk;
    }
    __syncthreads();

    const int w = tid >> 6, lane = tid & 63;
    const short8* pA = (const short8*)ldsA;
    const short8* pB = (const short8*)ldsB;

    f32x4 acc[NFN];
#pragma unroll
    for (int fn = 0; fn < NFN; ++fn) acc[fn] = (f32x4){0.f, 0.f, 0.f, 0.f};

#pragma unroll
    for (int fk = 0; fk < 4; ++fk) {
        const short8 a = pA[(w * 4 + fk) * 64 + lane];
#pragma unroll
        for (int fn = 0; fn < NFN; ++fn) {
            const short8 b = pB[(fn * 4 + fk) * 64 + lane];
            acc[fn] = __builtin_amdgcn_mfma_f32_16x16x32_bf16(a, b, acc[fn], 0, 0, 0);
        }
    }

    const int cn = lane & 15, rq = lane >> 4;
    float* C1f = (float*)C1v;
    unsigned short* C1h = (unsigned short*)C1v;
    unsigned short* C2h = (unsigned short*)C2v;
    float bv[NFN];
#pragma unroll
    for (int fn = 0; fn < NFN; ++fn) bv[fn] = bias ? bias[fn * 16 + cn] : 0.f;

    if (EPI == 0) {
#pragma unroll
        for (int reg = 0; reg < 4; ++reg) {
            const int gr = r0 + w * 16 + rq * 4 + reg;
            if (gr < nrows) {
#pragma unroll
                for (int fn = 0; fn < NFN; ++fn) {
                    const float v = acc[fn][reg] + bv[fn];
                    if (SPLIT) {
                        if (fn < 8) C1h[(size_t)gr * ld1 + fn * 16 + cn] = f2bf(v);
                        else        C2h[(size_t)gr * ld2 + (fn - 8) * 16 + cn] = f2bf(v);
                    } else if (OBF == 1) {
                        C1h[(size_t)gr * ld1 + fn * 16 + cn] = f2bf(v);
                    } else if (OBF == 2) {
                        C1f[(size_t)gr * ld1 + fn * 16 + cn] = v;
                        C2h[(size_t)gr * ld2 + fn * 16 + cn] = f2bf(v);
                    } else {
                        C1f[(size_t)gr * ld1 + fn * 16 + cn] = v;
                    }
                }
            }
        }
    } else {
        float gv[NFN], bbv[NFN];
#pragma unroll
        for (int fn = 0; fn < NFN; ++fn) { gv[fn] = lng[fn * 16 + cn]; bbv[fn] = lnb[fn * 16 + cn]; }
#pragma unroll
        for (int reg = 0; reg < 4; ++reg) {
            const int gr = r0 + w * 16 + rq * 4 + reg;
            const int grc = gr < nrows ? gr : nrows - 1;
            float val[NFN];
            float sum = 0.f, sq = 0.f;
#pragma unroll
            for (int fn = 0; fn < NFN; ++fn) {
                float v = acc[fn][reg] + bv[fn];
                if (EPI == 2) v = v * sigf(v);
                else          v += res[(size_t)grc * ld1 + fn * 16 + cn];
                val[fn] = v; sum += v; sq += v * v;
            }
#pragma unroll
            for (int m = 1; m < 16; m <<= 1) { sum += __shfl_xor(sum, m); sq += __shfl_xor(sq, m); }
            const float mean = sum * (1.f / 128.f);
            const float var = sq * (1.f / 128.f) - mean * mean;
            const float rstd = rsqrtf(var + LN_EPS);
            if (gr < nrows) {
#pragma unroll
                for (int fn = 0; fn < NFN; ++fn) {
                    const float v = (val[fn] - mean) * rstd * gv[fn] + bbv[fn];
                    if (OBF == 1) C1h[(size_t)gr * ld1 + fn * 16 + cn] = f2bf(v);
                    else          C1f[(size_t)gr * ld1 + fn * 16 + cn] = v;
                }
            }
        }
    }
}

// ---- counting sort of edges by row ----

__global__ __launch_bounds__(256)
void hist_k(const int* __restrict__ row, int* __restrict__ cnt, int E)
{
    for (int e = blockIdx.x * blockDim.x + threadIdx.x; e < E; e += gridDim.x * blockDim.x)
        atomicAdd(&cnt[row[e]], 1);
}

__global__ __launch_bounds__(1024)
void scan_a(const int* __restrict__ cnt, int* __restrict__ off,
            int* __restrict__ btot, int n)
{
    __shared__ int wsum[16];
    const int tid = threadIdx.x, lane = tid & 63, wv = tid >> 6;
    const int i = blockIdx.x * 1024 + tid;
    const int v = (i < n) ? cnt[i] : 0;
    int incl = v;
#pragma unroll
    for (int d = 1; d < 64; d <<= 1) { int t = __shfl_up(incl, d); if (lane >= d) incl += t; }
    if (lane == 63) wsum[wv] = incl;
    __syncthreads();
    if (tid == 0) {
        int run = 0;
        for (int ww = 0; ww < 16; ++ww) { int t = wsum[ww]; wsum[ww] = run; run += t; }
    }
    __syncthreads();
    if (i < n) off[i] = wsum[wv] + incl - v;
    if (tid == 1023) btot[blockIdx.x] = wsum[15] + incl;
}

__global__ __launch_bounds__(64)
void scan_b(int* __restrict__ btot, int* __restrict__ bexc,
            int* __restrict__ off, int n, int nb, int E)
{
    const int t = threadIdx.x;
    const int v = (t < nb) ? btot[t] : 0;
    int incl = v;
#pragma unroll
    for (int d = 1; d < 64; d <<= 1) { int u = __shfl_up(incl, d); if (t >= d) incl += u; }
    if (t < nb) bexc[t] = incl - v;
    if (t == 0) off[n] = E;
}

__global__ __launch_bounds__(1024)
void scan_c(int* __restrict__ off, const int* __restrict__ bexc,
            int* __restrict__ cursor, int n)
{
    const int i = blockIdx.x * 1024 + threadIdx.x;
    if (i < n) {
        const int o = off[i] + bexc[blockIdx.x];
        off[i] = o;
        cursor[i] = o;
    }
}

__global__ __launch_bounds__(256)
void scatter_k(const int* __restrict__ row, const int* __restrict__ col,
               const float* __restrict__ ea, const float* __restrict__ em,
               int* __restrict__ cursor, int* __restrict__ rowS,
               int* __restrict__ colS, float2* __restrict__ eamS, int E)
{
    for (int e = blockIdx.x * blockDim.x + threadIdx.x; e < E; e += gridDim.x * blockDim.x) {
        const int r = row[e];
        const int pos = atomicAdd(&cursor[r], 1);
        rowS[pos] = r;
        colS[pos] = col[e];
        eamS[pos] = make_float2(ea[e], em[e]);
    }
}

// ---- edge-parallel attention: catS[j] = (col, att) ----
// wave = 4 groups x 16 lanes; group g handles edge base+g; lane l = comps l*8..+8
__global__ __launch_bounds__(256)
void att_edge(const unsigned short* __restrict__ xrH,
              const unsigned short* __restrict__ xcH,
              const int* __restrict__ rowS, const int* __restrict__ colS,
              const float2* __restrict__ eamS, const float* __restrict__ we_,
              const float* __restrict__ w2_, const float* __restrict__ b2p,
              uint2* __restrict__ catS, int E)
{
    const int lane = threadIdx.x & 63;
    const int g = lane >> 4, l = lane & 15;
    const int gwid = (blockIdx.x * blockDim.x + threadIdx.x) >> 6;
    const int nw = (gridDim.x * blockDim.x) >> 6;

    float we[8], w2[8];
    {
        float4 a = ((const float4*)we_)[l * 2], b = ((const float4*)we_)[l * 2 + 1];
        we[0] = a.x; we[1] = a.y; we[2] = a.z; we[3] = a.w;
        we[4] = b.x; we[5] = b.y; we[6] = b.z; we[7] = b.w;
        float4 c = ((const float4*)w2_)[l * 2], d = ((const float4*)w2_)[l * 2 + 1];
        w2[0] = c.x; w2[1] = c.y; w2[2] = c.z; w2[3] = c.w;
        w2[4] = d.x; w2[5] = d.y; w2[6] = d.z; w2[7] = d.w;
    }
    const float b2 = *b2p;

    for (int base = gwid * 4; base < E; base += nw * 4) {
        const int j = base + g;
        const bool valid = j < E;
        const int jc = valid ? j : E - 1;
        const int r = rowS[jc], c = colS[jc];
        const float2 eam = eamS[jc];
        float xr[8], xc[8];
        bf8f(((const uint4*)(xrH + (size_t)r * 128))[l], xr);
        bf8f(((const uint4*)(xcH + (size_t)c * 128))[l], xc);
        float p = 0.f;
#pragma unroll
        for (int i = 0; i < 8; ++i) {
            const float t = xr[i] + xc[i] + eam.x * we[i];
            p += t * sigf(t) * w2[i];
        }
#pragma unroll
        for (int m = 1; m < 16; m <<= 1) p += __shfl_xor(p, m);
        const float att = sigf(p + b2) * eam.y;
        if (valid && l == 0) catS[j] = make_uint2((unsigned)c, __float_as_uint(att));
    }
}

// ---- row accumulation (no MLP): msg[r] = sum att * xm[col] ----
// wave grid-strides over rows; 4 groups x 16 lanes; group g -> one edge
__global__ __launch_bounds__(256)
void accum_k(const unsigned short* __restrict__ xmH, const int* __restrict__ off,
             const uint2* __restrict__ catS, float* __restrict__ msg, int N)
{
    const int lane = threadIdx.x & 63;
    const int g = lane >> 4, l = lane & 15;
    const int gwid = (blockIdx.x * blockDim.x + threadIdx.x) >> 6;
    const int nw = (gridDim.x * blockDim.x) >> 6;
    const uint4* xm4 = (const uint4*)xmH;

    for (int wid = gwid; wid < N; wid += nw) {
        int j0 = off[wid];
        const int jend = off[wid + 1];
        float acc[8] = {0.f, 0.f, 0.f, 0.f, 0.f, 0.f, 0.f, 0.f};

        for (; j0 + 8 <= jend; j0 += 8) {
            const uint2 caA = catS[j0 + g];
            const uint2 caB = catS[j0 + 4 + g];
            const uint4 pA = xm4[(size_t)caA.x * 16 + l];
            const uint4 pB = xm4[(size_t)caB.x * 16 + l];
            const float attA = __uint_as_float(caA.y);
            const float attB = __uint_as_float(caB.y);
            float xmA[8], xmB[8];
            bf8f(pA, xmA); bf8f(pB, xmB);
#pragma unroll
            for (int i = 0; i < 8; ++i)
                acc[i] = fmaf(attB, xmB[i], fmaf(attA, xmA[i], acc[i]));
        }
        for (; j0 < jend; j0 += 4) {
            const int je = j0 + g;
            const bool valid = je < jend;
            const int jc = valid ? je : jend - 1;
            const uint2 ca = catS[jc];
            const uint4 p = xm4[(size_t)ca.x * 16 + l];
            const float att = valid ? __uint_as_float(ca.y) : 0.f;
            float xm[8];
            bf8f(p, xm);
#pragma unroll
            for (int i = 0; i < 8; ++i) acc[i] = fmaf(att, xm[i], acc[i]);
        }

#pragma unroll
        for (int i = 0; i < 8; ++i) {
            acc[i] += __shfl_xor(acc[i], 16);
            acc[i] += __shfl_xor(acc[i], 32);
        }
        if (g == 0) {
            float* mrow = msg + (size_t)wid * 128 + l * 8;
            *(float4*)mrow = {acc[0], acc[1], acc[2], acc[3]};
            *(float4*)(mrow + 4) = {acc[4], acc[5], acc[6], acc[7]};
        }
    }
}

extern "C" void kernel_launch(void* const* d_in, const int* in_sizes, int n_in,
                              void* d_out, int out_size, void* d_ws, size_t ws_size,
                              hipStream_t stream)
{
    const float* h        = (const float*)d_in[0];
    const float* edge_attr= (const float*)d_in[1];
    const int*   row      = (const int*)d_in[2];
    const int*   col      = (const int*)d_in[3];
    const float* edge_mask= (const float*)d_in[5];
    const float* lin_w    = (const float*)d_in[6];
    const float* lin_b    = (const float*)d_in[7];
    const float* msg_w1   = (const float*)d_in[8];
    const float* msg_b1   = (const float*)d_in[9];
    const float* msg_ln_g = (const float*)d_in[10];
    const float* msg_ln_b = (const float*)d_in[11];
    const float* msg_w2   = (const float*)d_in[12];
    const float* msg_b2   = (const float*)d_in[13];
    const float* att_w1   = (const float*)d_in[14];
    const float* att_b1   = (const float*)d_in[15];
    const float* att_w2   = (const float*)d_in[16];
    const float* att_b2   = (const float*)d_in[17];
    const float* out_w1   = (const float*)d_in[18];
    const float* out_b1   = (const float*)d_in[19];
    const float* out_ln_g = (const float*)d_in[20];
    const float* out_ln_b = (const float*)d_in[21];
    const float* out_w2   = (const float*)d_in[22];
    const float* out_b2   = (const float*)d_in[23];
    const float* ln_g     = (const float*)d_in[24];
    const float* ln_b     = (const float*)d_in[25];

    const int N = in_sizes[0] / 128;
    const int E = in_sizes[2];
    const size_t NF = (size_t)N * 128;

    float* x    = (float*)d_ws;                         // f32 [N][128]
    float* msg  = x + NF;                               // f32 [N][128]
    unsigned short* hb  = (unsigned short*)(msg + NF);  // bf16 [N][128] h1n / o1
    unsigned short* xbH = hb + NF;                      // bf16 [N][128] copy of x
    unsigned short* xrH = xbH + NF;                     // bf16 [N][128]
    unsigned short* xcH = xrH + NF;                     // bf16 [N][128]
    unsigned short* xmH = xcH + NF;                     // bf16 [N][128]
    int*    cnt   = (int*)(xmH + NF);                   // N (reused as cursor)
    int*    off   = cnt + N;                            // N+1 (alloc N+8)
    int*    btot  = off + N + 8;                        // 64
    int*    bexc  = btot + 64;                          // 64
    int*    rowS  = bexc + 64;                          // E
    int*    colS  = rowS + E;                           // E
    float2* eamS  = (float2*)(colS + E);                // E
    uint2*  catS  = (uint2*)(eamS + E);                 // E
    unsigned short* wp = (unsigned short*)(catS + E);   // 8*16384 bf16
    float* bias256 = (float*)(wp + 8 * 16384);

    const int gb = (N + 63) / 64;
    const int nb = (N + 1023) / 1024;
    const size_t LDS8  = (1024 + 8 * 256) * sizeof(uint4);  // 48 KiB
    const size_t LDS16 = (1024 + 16 * 256) * sizeof(uint4); // 80 KiB

    prep_w<<<513, 256, 0, stream>>>(lin_w, msg_w1, msg_w2, att_w1, out_w1, out_w2,
                                    att_b1, wp, bias256);
    hipMemsetAsync(cnt, 0, (size_t)N * sizeof(int), stream);
    hist_k<<<1024, 256, 0, stream>>>(row, cnt, E);
    scan_a<<<nb, 1024, 0, stream>>>(cnt, off, btot, N);
    scan_b<<<1, 64, 0, stream>>>(btot, bexc, off, N, nb, E);
    scan_c<<<nb, 1024, 0, stream>>>(off, bexc, cnt, N);
    scatter_k<<<1024, 256, 0, stream>>>(row, col, edge_attr, edge_mask,
                                        cnt, rowS, colS, eamS, E);

    // x = h @ lin_w + lin_b                    (f32 out + bf16 copy)
    gemm_mfma<0, 8, 0, 2, 0><<<gb, 256, LDS8, stream>>>(h, wp, lin_b, nullptr, nullptr, nullptr,
                                                        x, 128, xbH, 128, N);
    // xr|xc = x @ att_w1[0:256] + [b1|0]       (split destinations)
    gemm_mfma<0, 16, 1, 1, 1><<<gb, 256, LDS16, stream>>>(xbH, wp + 3 * 16384, bias256, nullptr, nullptr, nullptr,
                                                          xrH, 128, xcH, 128, N);
    // att scalars for every edge (sorted order)
    att_edge<<<2048, 256, 0, stream>>>(xrH, xcH, rowS, colS, eamS,
                                       att_w1 + 256 * 128, att_w2, att_b2, catS, E);

    // h1n = LN(silu(x @ msg_w1 + msg_b1))
    gemm_mfma<2, 8, 1, 1, 0><<<gb, 256, LDS8, stream>>>(xbH, wp + 16384, msg_b1, msg_ln_g, msg_ln_b, nullptr,
                                                        hb, 128, nullptr, 0, N);
    // xm = h1n @ msg_w2 + msg_b2
    gemm_mfma<0, 8, 1, 1, 0><<<gb, 256, LDS8, stream>>>(hb, wp + 2 * 16384, msg_b2, nullptr, nullptr, nullptr,
                                                        xmH, 128, nullptr, 0, N);

    // msg[r] = sum att * xm[col]
    accum_k<<<2048, 256, 0, stream>>>(xmH, off, catS, msg, N);

    // o1 = LN(silu(msg @ out_w1 + out_b1))
    gemm_mfma<2, 8, 0, 1, 0><<<gb, 256, LDS8, stream>>>(msg, wp + 5 * 16384, out_b1, out_ln_g, out_ln_b, nullptr,
                                                        hb, 128, nullptr, 0, N);
    // out = LN(x + o1 @ out_w2 + out_b2) * ln_g + ln_b
    gemm_mfma<3, 8, 1, 0, 0><<<gb, 256, LDS8, stream>>>(hb, wp + 6 * 16384, out_b2, ln_g, ln_b, x,
                                                        (float*)d_out, 128, nullptr, 0, N);
}

// Round 7
// 298.515 us; speedup vs baseline: 1.0668x; 1.0668x over previous
//
#include <hip/hip_runtime.h>

#define LN_EPS 1e-5f

typedef __attribute__((ext_vector_type(8))) short short8;
typedef __attribute__((ext_vector_type(4))) float f32x4;

__device__ __forceinline__ float sigf(float x) { return 1.0f / (1.0f + __expf(-x)); }

__device__ __forceinline__ unsigned short f2bf(float f) {
    unsigned u = __float_as_uint(f);
    return (unsigned short)((u + 0x7fffu + ((u >> 16) & 1u)) >> 16);
}
__device__ __forceinline__ unsigned f2bf2(float lo, float hi) {
    return (unsigned)f2bf(lo) | ((unsigned)f2bf(hi) << 16);
}
__device__ __forceinline__ void bf2f(unsigned u, float& lo, float& hi) {
    lo = __uint_as_float(u << 16);
    hi = __uint_as_float(u & 0xffff0000u);
}
__device__ __forceinline__ void bf8f(uint4 p, float* o) {
    bf2f(p.x, o[0], o[1]); bf2f(p.y, o[2], o[3]);
    bf2f(p.z, o[4], o[5]); bf2f(p.w, o[6], o[7]);
}

// butterfly sum over each quad (lanes 4k..4k+3) via DPP quad_perm — no DS ops
__device__ __forceinline__ float quad_add_all(float x) {
    int v = __builtin_amdgcn_update_dpp(0, __float_as_int(x), 0xB1, 0xF, 0xF, true); // [1,0,3,2]
    x += __int_as_float(v);
    v = __builtin_amdgcn_update_dpp(0, __float_as_int(x), 0x4E, 0xF, 0xF, true);     // [2,3,0,1]
    x += __int_as_float(v);
    return x;
}

// ---- weight prep: f32 [128][128] row-major -> fragment-linear bf16 ----
__global__ __launch_bounds__(256)
void prep_w(const float* __restrict__ lin_w, const float* __restrict__ msg_w1,
            const float* __restrict__ msg_w2, const float* __restrict__ att_w1,
            const float* __restrict__ out_w1, const float* __restrict__ out_w2,
            const float* __restrict__ att_b1, unsigned short* __restrict__ wp,
            float* __restrict__ bias256)
{
    const int idx = blockIdx.x * 256 + threadIdx.x;
    if (idx < 8 * 16384) {
        const int m = idx >> 14, r = idx & 16383;
        const int k = r >> 7, n = r & 127;
        const float* src; int slot; int fnBase = 0;
        switch (m) {
            case 0: src = lin_w;  slot = 0; break;
            case 1: src = msg_w1; slot = 1; break;
            case 2: src = msg_w2; slot = 2; break;
            case 3: src = att_w1; slot = 3; break;
            case 4: src = att_w1 + 128 * 128; slot = 3; fnBase = 8; break;
            case 5: src = out_w1; slot = 5; break;
            default: src = out_w2; slot = 6; break;
        }
        const float v = src[k * 128 + n];
        const int fn = fnBase + (n >> 4);
        const int fk = k >> 5, kb = (k >> 3) & 3, j = k & 7;
        const size_t dst = (size_t)slot * 16384 + ((size_t)((fn * 4 + fk) * 64 + (n & 15) + 16 * kb)) * 8 + j;
        wp[dst] = f2bf(v);
    } else if (idx < 8 * 16384 + 256) {
        const int t = idx - 8 * 16384;
        bias256[t] = (t < 128) ? att_b1[t] : 0.f;
    }
}

// ---- A-fragment loaders (direct from row-major global, no LDS) ----
__device__ __forceinline__ short8 ldA_bf(const unsigned short* A, size_t row, int k0) {
    return *(const short8*)(A + row * 128 + k0);
}
__device__ __forceinline__ short8 ldA_f32(const float* A, size_t row, int k0) {
    const float* ap = A + row * 128 + k0;
    const float4 f0 = *(const float4*)ap;
    const float4 f1 = *(const float4*)(ap + 4);
    union { unsigned u[4]; short8 s; } v;
    v.u[0] = f2bf2(f0.x, f0.y); v.u[1] = f2bf2(f0.z, f0.w);
    v.u[2] = f2bf2(f1.x, f1.y); v.u[3] = f2bf2(f1.z, f1.w);
    return v.s;
}

// ---- barrier-free bf16 MFMA GEMM: epi(A[N,128] @ W + bias) ----
// A-frags direct from global (row-major); B-frags direct from frag-linear Wp.
// ABF: A bf16.  OBF: 0 = f32 C1; 1 = bf16 C1; 2 = f32 C1 + bf16 copy C2.
// SPLIT (NFN=16): fn<8 -> bf16 C1, fn>=8 -> bf16 C2 (fn rebased).
// EPI 0: +bias; EPI 2: silu(.+bias) then LN; EPI 3: (.+bias+res) then LN
template<int EPI, int NFN, int ABF, int OBF, int SPLIT>
__global__ __launch_bounds__(256, NFN == 8 ? 4 : 3)
void gemm_mfma(const void* __restrict__ Av, const unsigned short* __restrict__ Wp,
               const float* __restrict__ bias, const float* __restrict__ lng,
               const float* __restrict__ lnb, const float* __restrict__ res,
               void* __restrict__ C1v, int ld1, void* __restrict__ C2v, int ld2,
               int nrows)
{
    const int tid = threadIdx.x;
    const int w = tid >> 6, lane = tid & 63;
    const int r0 = blockIdx.x * 64;
    const int arow = r0 + w * 16 + (lane & 15);
    const size_t rowc = (arow < nrows) ? (size_t)arow : (size_t)(nrows - 1);
    const int kh = (lane >> 4) * 8;

    short8 a[4];
#pragma unroll
    for (int fk = 0; fk < 4; ++fk)
        a[fk] = ABF ? ldA_bf((const unsigned short*)Av, rowc, fk * 32 + kh)
                    : ldA_f32((const float*)Av, rowc, fk * 32 + kh);

    const short8* Bf = (const short8*)Wp;
    f32x4 acc[NFN];
#pragma unroll
    for (int fn = 0; fn < NFN; ++fn) acc[fn] = (f32x4){0.f, 0.f, 0.f, 0.f};
#pragma unroll
    for (int fk = 0; fk < 4; ++fk)
#pragma unroll
        for (int fn = 0; fn < NFN; ++fn)
            acc[fn] = __builtin_amdgcn_mfma_f32_16x16x32_bf16(a[fk], Bf[(fn * 4 + fk) * 64 + lane], acc[fn], 0, 0, 0);

    const int cn = lane & 15, rq = lane >> 4;
    float* C1f = (float*)C1v;
    unsigned short* C1h = (unsigned short*)C1v;
    unsigned short* C2h = (unsigned short*)C2v;
    float bv[NFN];
#pragma unroll
    for (int fn = 0; fn < NFN; ++fn) bv[fn] = bias ? bias[fn * 16 + cn] : 0.f;

    if (EPI == 0) {
#pragma unroll
        for (int reg = 0; reg < 4; ++reg) {
            const int gr = r0 + w * 16 + rq * 4 + reg;
            if (gr < nrows) {
#pragma unroll
                for (int fn = 0; fn < NFN; ++fn) {
                    const float v = acc[fn][reg] + bv[fn];
                    if (SPLIT) {
                        if (fn < 8) C1h[(size_t)gr * ld1 + fn * 16 + cn] = f2bf(v);
                        else        C2h[(size_t)gr * ld2 + (fn - 8) * 16 + cn] = f2bf(v);
                    } else if (OBF == 1) {
                        C1h[(size_t)gr * ld1 + fn * 16 + cn] = f2bf(v);
                    } else if (OBF == 2) {
                        C1f[(size_t)gr * ld1 + fn * 16 + cn] = v;
                        C2h[(size_t)gr * ld2 + fn * 16 + cn] = f2bf(v);
                    } else {
                        C1f[(size_t)gr * ld1 + fn * 16 + cn] = v;
                    }
                }
            }
        }
    } else {
        float gv[NFN], bbv[NFN];
#pragma unroll
        for (int fn = 0; fn < NFN; ++fn) { gv[fn] = lng[fn * 16 + cn]; bbv[fn] = lnb[fn * 16 + cn]; }
#pragma unroll
        for (int reg = 0; reg < 4; ++reg) {
            const int gr = r0 + w * 16 + rq * 4 + reg;
            const int grc = gr < nrows ? gr : nrows - 1;
            float val[NFN];
            float sum = 0.f, sq = 0.f;
#pragma unroll
            for (int fn = 0; fn < NFN; ++fn) {
                float v = acc[fn][reg] + bv[fn];
                if (EPI == 2) v = v * sigf(v);
                else          v += res[(size_t)grc * ld1 + fn * 16 + cn];
                val[fn] = v; sum += v; sq += v * v;
            }
#pragma unroll
            for (int m = 1; m < 16; m <<= 1) { sum += __shfl_xor(sum, m); sq += __shfl_xor(sq, m); }
            const float mean = sum * (1.f / 128.f);
            const float var = sq * (1.f / 128.f) - mean * mean;
            const float rstd = rsqrtf(var + LN_EPS);
            if (gr < nrows) {
#pragma unroll
                for (int fn = 0; fn < NFN; ++fn) {
                    const float v = (val[fn] - mean) * rstd * gv[fn] + bbv[fn];
                    if (OBF == 1) C1h[(size_t)gr * ld1 + fn * 16 + cn] = f2bf(v);
                    else          C1f[(size_t)gr * ld1 + fn * 16 + cn] = v;
                }
            }
        }
    }
}

// ---- fused double GEMM: C = epi2( LN(silu(A@W1+b1)) @ W2 + b2 ) ----
// Stage-1 output handed off per-wave via XOR-swizzled LDS (no barrier).
// EPI2 0: +b2, bf16 C.  EPI2 3: +b2+res then LN(ln2), f32 C.
template<int ABF, int EPI2>
__global__ __launch_bounds__(256, 4)
void gemm2_mfma(const void* __restrict__ Av,
                const unsigned short* __restrict__ Wp1, const float* __restrict__ b1,
                const float* __restrict__ ln1g, const float* __restrict__ ln1b,
                const unsigned short* __restrict__ Wp2, const float* __restrict__ b2,
                const float* __restrict__ ln2g, const float* __restrict__ ln2b,
                const float* __restrict__ res, void* __restrict__ Cv, int nrows)
{
    __shared__ unsigned short hof[4 * 2048];   // 16 KiB, 4 KiB per wave
    const int tid = threadIdx.x;
    const int w = tid >> 6, lane = tid & 63;
    const int r0 = blockIdx.x * 64;
    const int arow = r0 + w * 16 + (lane & 15);
    const size_t rowc = (arow < nrows) ? (size_t)arow : (size_t)(nrows - 1);
    const int kh = (lane >> 4) * 8;
    const int cn = lane & 15, rq = lane >> 4;

    short8 a[4];
#pragma unroll
    for (int fk = 0; fk < 4; ++fk)
        a[fk] = ABF ? ldA_bf((const unsigned short*)Av, rowc, fk * 32 + kh)
                    : ldA_f32((const float*)Av, rowc, fk * 32 + kh);

    const short8* B1f = (const short8*)Wp1;
    f32x4 acc[8];
#pragma unroll
    for (int fn = 0; fn < 8; ++fn) acc[fn] = (f32x4){0.f, 0.f, 0.f, 0.f};
#pragma unroll
    for (int fk = 0; fk < 4; ++fk)
#pragma unroll
        for (int fn = 0; fn < 8; ++fn)
            acc[fn] = __builtin_amdgcn_mfma_f32_16x16x32_bf16(a[fk], B1f[(fn * 4 + fk) * 64 + lane], acc[fn], 0, 0, 0);

    // epilogue-1: silu + LN -> wave-private swizzled LDS handoff
    unsigned short* hw = hof + w * 2048;
    {
        float bv[8], gv[8], bbv[8];
#pragma unroll
        for (int fn = 0; fn < 8; ++fn) {
            bv[fn] = b1[fn * 16 + cn]; gv[fn] = ln1g[fn * 16 + cn]; bbv[fn] = ln1b[fn * 16 + cn];
        }
#pragma unroll
        for (int reg = 0; reg < 4; ++reg) {
            float val[8];
            float sum = 0.f, sq = 0.f;
#pragma unroll
            for (int fn = 0; fn < 8; ++fn) {
                float v = acc[fn][reg] + bv[fn];
                v = v * sigf(v);
                val[fn] = v; sum += v; sq += v * v;
            }
#pragma unroll
            for (int m = 1; m < 16; m <<= 1) { sum += __shfl_xor(sum, m); sq += __shfl_xor(sq, m); }
            const float mean = sum * (1.f / 128.f);
            const float var = sq * (1.f / 128.f) - mean * mean;
            const float rstd = rsqrtf(var + LN_EPS);
            const int row16 = rq * 4 + reg;
            const int sw = (row16 & 7) << 3;           // XOR swizzle (ushort units)
#pragma unroll
            for (int fn = 0; fn < 8; ++fn) {
                const float o = (val[fn] - mean) * rstd * gv[fn] + bbv[fn];
                hw[row16 * 128 + ((fn * 16 + cn) ^ sw)] = f2bf(o);
            }
        }
    }

    // stage-2 A frags from handoff (compiler inserts lgkmcnt wait; intra-wave only)
    short8 a2[4];
    {
        const int row16 = lane & 15;
        const int sw = (row16 & 7) << 3;
#pragma unroll
        for (int fk = 0; fk < 4; ++fk)
            a2[fk] = *(const short8*)(hw + row16 * 128 + ((fk * 32 + kh) ^ sw));
    }

    const short8* B2f = (const short8*)Wp2;
    f32x4 acc2[8];
#pragma unroll
    for (int fn = 0; fn < 8; ++fn) acc2[fn] = (f32x4){0.f, 0.f, 0.f, 0.f};
#pragma unroll
    for (int fk = 0; fk < 4; ++fk)
#pragma unroll
        for (int fn = 0; fn < 8; ++fn)
            acc2[fn] = __builtin_amdgcn_mfma_f32_16x16x32_bf16(a2[fk], B2f[(fn * 4 + fk) * 64 + lane], acc2[fn], 0, 0, 0);

    // epilogue-2
    float bv2[8];
#pragma unroll
    for (int fn = 0; fn < 8; ++fn) bv2[fn] = b2[fn * 16 + cn];

    if (EPI2 == 0) {
        unsigned short* Ch = (unsigned short*)Cv;
#pragma unroll
        for (int reg = 0; reg < 4; ++reg) {
            const int gr = r0 + w * 16 + rq * 4 + reg;
            if (gr < nrows) {
#pragma unroll
                for (int fn = 0; fn < 8; ++fn)
                    Ch[(size_t)gr * 128 + fn * 16 + cn] = f2bf(acc2[fn][reg] + bv2[fn]);
            }
        }
    } else {
        float* Cf = (float*)Cv;
        float gv[8], bbv[8];
#pragma unroll
        for (int fn = 0; fn < 8; ++fn) { gv[fn] = ln2g[fn * 16 + cn]; bbv[fn] = ln2b[fn * 16 + cn]; }
#pragma unroll
        for (int reg = 0; reg < 4; ++reg) {
            const int gr = r0 + w * 16 + rq * 4 + reg;
            const int grc = gr < nrows ? gr : nrows - 1;
            float val[8];
            float sum = 0.f, sq = 0.f;
#pragma unroll
            for (int fn = 0; fn < 8; ++fn) {
                float v = acc2[fn][reg] + bv2[fn] + res[(size_t)grc * 128 + fn * 16 + cn];
                val[fn] = v; sum += v; sq += v * v;
            }
#pragma unroll
            for (int m = 1; m < 16; m <<= 1) { sum += __shfl_xor(sum, m); sq += __shfl_xor(sq, m); }
            const float mean = sum * (1.f / 128.f);
            const float var = sq * (1.f / 128.f) - mean * mean;
            const float rstd = rsqrtf(var + LN_EPS);
            if (gr < nrows) {
#pragma unroll
                for (int fn = 0; fn < 8; ++fn)
                    Cf[(size_t)gr * 128 + fn * 16 + cn] = (val[fn] - mean) * rstd * gv[fn] + bbv[fn];
            }
        }
    }
}

// ---- counting sort of edges by row ----

__global__ __launch_bounds__(256)
void hist_k(const int* __restrict__ row, int* __restrict__ cnt, int E)
{
    for (int e = blockIdx.x * blockDim.x + threadIdx.x; e < E; e += gridDim.x * blockDim.x)
        atomicAdd(&cnt[row[e]], 1);
}

__global__ __launch_bounds__(1024)
void scan_a(const int* __restrict__ cnt, int* __restrict__ off,
            int* __restrict__ btot, int n)
{
    __shared__ int wsum[16];
    const int tid = threadIdx.x, lane = tid & 63, wv = tid >> 6;
    const int i = blockIdx.x * 1024 + tid;
    const int v = (i < n) ? cnt[i] : 0;
    int incl = v;
#pragma unroll
    for (int d = 1; d < 64; d <<= 1) { int t = __shfl_up(incl, d); if (lane >= d) incl += t; }
    if (lane == 63) wsum[wv] = incl;
    __syncthreads();
    if (tid == 0) {
        int run = 0;
        for (int ww = 0; ww < 16; ++ww) { int t = wsum[ww]; wsum[ww] = run; run += t; }
    }
    __syncthreads();
    if (i < n) off[i] = wsum[wv] + incl - v;
    if (tid == 1023) btot[blockIdx.x] = wsum[15] + incl;
}

__global__ __launch_bounds__(64)
void scan_b(int* __restrict__ btot, int* __restrict__ bexc,
            int* __restrict__ off, int n, int nb, int E)
{
    const int t = threadIdx.x;
    const int v = (t < nb) ? btot[t] : 0;
    int incl = v;
#pragma unroll
    for (int d = 1; d < 64; d <<= 1) { int u = __shfl_up(incl, d); if (t >= d) incl += u; }
    if (t < nb) bexc[t] = incl - v;
    if (t == 0) off[n] = E;
}

__global__ __launch_bounds__(1024)
void scan_c(int* __restrict__ off, const int* __restrict__ bexc,
            int* __restrict__ cursor, int n)
{
    const int i = blockIdx.x * 1024 + threadIdx.x;
    if (i < n) {
        const int o = off[i] + bexc[blockIdx.x];
        off[i] = o;
        cursor[i] = o;
    }
}

__global__ __launch_bounds__(256)
void scatter_k(const int* __restrict__ row, const int* __restrict__ col,
               const float* __restrict__ ea, const float* __restrict__ em,
               int* __restrict__ cursor, int* __restrict__ rowS,
               int* __restrict__ colS, float2* __restrict__ eamS, int E)
{
    for (int e = blockIdx.x * blockDim.x + threadIdx.x; e < E; e += gridDim.x * blockDim.x) {
        const int r = row[e];
        const int pos = atomicAdd(&cursor[r], 1);
        rowS[pos] = r;
        colS[pos] = col[e];
        eamS[pos] = make_float2(ea[e], em[e]);
    }
}

// ---- edge-parallel attention, quad-per-edge ----
// lane quad q=lane&3 owns comps {ch*32 + q*8 + i}; 16 edges per wave; DPP reduce.
__global__ __launch_bounds__(256, 4)
void att_edge(const unsigned short* __restrict__ xrH,
              const unsigned short* __restrict__ xcH,
              const int* __restrict__ rowS, const int* __restrict__ colS,
              const float2* __restrict__ eamS, const float* __restrict__ we_,
              const float* __restrict__ w2_, const float* __restrict__ b2p,
              uint2* __restrict__ catS, int E)
{
    const int lane = threadIdx.x & 63;
    const int q = lane & 3;
    const int gwid = (blockIdx.x * blockDim.x + threadIdx.x) >> 6;
    const int nw = (gridDim.x * blockDim.x) >> 6;

    float we[32], w2[32];
#pragma unroll
    for (int ch = 0; ch < 4; ++ch) {
        const float4 a0 = ((const float4*)we_)[ch * 8 + q * 2];
        const float4 a1 = ((const float4*)we_)[ch * 8 + q * 2 + 1];
        we[ch * 8 + 0] = a0.x; we[ch * 8 + 1] = a0.y; we[ch * 8 + 2] = a0.z; we[ch * 8 + 3] = a0.w;
        we[ch * 8 + 4] = a1.x; we[ch * 8 + 5] = a1.y; we[ch * 8 + 6] = a1.z; we[ch * 8 + 7] = a1.w;
        const float4 c0 = ((const float4*)w2_)[ch * 8 + q * 2];
        const float4 c1 = ((const float4*)w2_)[ch * 8 + q * 2 + 1];
        w2[ch * 8 + 0] = c0.x; w2[ch * 8 + 1] = c0.y; w2[ch * 8 + 2] = c0.z; w2[ch * 8 + 3] = c0.w;
        w2[ch * 8 + 4] = c1.x; w2[ch * 8 + 5] = c1.y; w2[ch * 8 + 6] = c1.z; w2[ch * 8 + 7] = c1.w;
    }
    const float b2 = *b2p;

    for (int base = gwid * 16; base < E; base += nw * 16) {
        const int e = base + (lane >> 2);
        const bool valid = e < E;
        const int ec = valid ? e : E - 1;
        const int r = rowS[ec], c = colS[ec];
        const float2 eam = eamS[ec];
        const unsigned short* xr = xrH + (size_t)r * 128;
        const unsigned short* xc = xcH + (size_t)c * 128;
        float p = 0.f;
#pragma unroll
        for (int ch = 0; ch < 4; ++ch) {
            const uint4 pa = *(const uint4*)(xr + ch * 32 + q * 8);
            const uint4 pb = *(const uint4*)(xc + ch * 32 + q * 8);
            float xa[8], xb[8];
            bf8f(pa, xa); bf8f(pb, xb);
#pragma unroll
            for (int i = 0; i < 8; ++i) {
                const float t = xa[i] + xb[i] + eam.x * we[ch * 8 + i];
                p += t * sigf(t) * w2[ch * 8 + i];
            }
        }
        p = quad_add_all(p);
        const float att = sigf(p + b2) * eam.y;
        if (valid && q == 0) catS[e] = make_uint2((unsigned)c, __float_as_uint(att));
    }
}

// ---- row accumulation: msg[r] = sum att * xm[col] ----
__global__ __launch_bounds__(256)
void accum_k(const unsigned short* __restrict__ xmH, const int* __restrict__ off,
             const uint2* __restrict__ catS, float* __restrict__ msg, int N)
{
    const int lane = threadIdx.x & 63;
    const int g = lane >> 4, l = lane & 15;
    const int gwid = (blockIdx.x * blockDim.x + threadIdx.x) >> 6;
    const int nw = (gridDim.x * blockDim.x) >> 6;
    const uint4* xm4 = (const uint4*)xmH;

    for (int wid = gwid; wid < N; wid += nw) {
        int j0 = off[wid];
        const int jend = off[wid + 1];
        float acc[8] = {0.f, 0.f, 0.f, 0.f, 0.f, 0.f, 0.f, 0.f};

        for (; j0 + 8 <= jend; j0 += 8) {
            const uint2 caA = catS[j0 + g];
            const uint2 caB = catS[j0 + 4 + g];
            const uint4 pA = xm4[(size_t)caA.x * 16 + l];
            const uint4 pB = xm4[(size_t)caB.x * 16 + l];
            const float attA = __uint_as_float(caA.y);
            const float attB = __uint_as_float(caB.y);
            float xmA[8], xmB[8];
            bf8f(pA, xmA); bf8f(pB, xmB);
#pragma unroll
            for (int i = 0; i < 8; ++i)
                acc[i] = fmaf(attB, xmB[i], fmaf(attA, xmA[i], acc[i]));
        }
        for (; j0 < jend; j0 += 4) {
            const int je = j0 + g;
            const bool valid = je < jend;
            const int jc = valid ? je : jend - 1;
            const uint2 ca = catS[jc];
            const uint4 p = xm4[(size_t)ca.x * 16 + l];
            const float att = valid ? __uint_as_float(ca.y) : 0.f;
            float xm[8];
            bf8f(p, xm);
#pragma unroll
            for (int i = 0; i < 8; ++i) acc[i] = fmaf(att, xm[i], acc[i]);
        }

#pragma unroll
        for (int i = 0; i < 8; ++i) {
            acc[i] += __shfl_xor(acc[i], 16);
            acc[i] += __shfl_xor(acc[i], 32);
        }
        if (g == 0) {
            float* mrow = msg + (size_t)wid * 128 + l * 8;
            *(float4*)mrow = {acc[0], acc[1], acc[2], acc[3]};
            *(float4*)(mrow + 4) = {acc[4], acc[5], acc[6], acc[7]};
        }
    }
}

extern "C" void kernel_launch(void* const* d_in, const int* in_sizes, int n_in,
                              void* d_out, int out_size, void* d_ws, size_t ws_size,
                              hipStream_t stream)
{
    const float* h        = (const float*)d_in[0];
    const float* edge_attr= (const float*)d_in[1];
    const int*   row      = (const int*)d_in[2];
    const int*   col      = (const int*)d_in[3];
    const float* edge_mask= (const float*)d_in[5];
    const float* lin_w    = (const float*)d_in[6];
    const float* lin_b    = (const float*)d_in[7];
    const float* msg_w1   = (const float*)d_in[8];
    const float* msg_b1   = (const float*)d_in[9];
    const float* msg_ln_g = (const float*)d_in[10];
    const float* msg_ln_b = (const float*)d_in[11];
    const float* msg_w2   = (const float*)d_in[12];
    const float* msg_b2   = (const float*)d_in[13];
    const float* att_w1   = (const float*)d_in[14];
    const float* att_b1   = (const float*)d_in[15];
    const float* att_w2   = (const float*)d_in[16];
    const float* att_b2   = (const float*)d_in[17];
    const float* out_w1   = (const float*)d_in[18];
    const float* out_b1   = (const float*)d_in[19];
    const float* out_ln_g = (const float*)d_in[20];
    const float* out_ln_b = (const float*)d_in[21];
    const float* out_w2   = (const float*)d_in[22];
    const float* out_b2   = (const float*)d_in[23];
    const float* ln_g     = (const float*)d_in[24];
    const float* ln_b     = (const float*)d_in[25];

    const int N = in_sizes[0] / 128;
    const int E = in_sizes[2];
    const size_t NF = (size_t)N * 128;

    float* x    = (float*)d_ws;                         // f32 [N][128]
    float* msg  = x + NF;                               // f32 [N][128]
    unsigned short* hb  = (unsigned short*)(msg + NF);  // (unused, layout keep)
    unsigned short* xbH = hb + NF;                      // bf16 [N][128] copy of x
    unsigned short* xrH = xbH + NF;                     // bf16 [N][128]
    unsigned short* xcH = xrH + NF;                     // bf16 [N][128]
    unsigned short* xmH = xcH + NF;                     // bf16 [N][128]
    int*    cnt   = (int*)(xmH + NF);                   // N (reused as cursor)
    int*    off   = cnt + N;                            // N+1 (alloc N+8)
    int*    btot  = off + N + 8;                        // 64
    int*    bexc  = btot + 64;                          // 64
    int*    rowS  = bexc + 64;                          // E
    int*    colS  = rowS + E;                           // E
    float2* eamS  = (float2*)(colS + E);                // E
    uint2*  catS  = (uint2*)(eamS + E);                 // E
    unsigned short* wp = (unsigned short*)(catS + E);   // 8*16384 bf16
    float* bias256 = (float*)(wp + 8 * 16384);

    const int gb = (N + 63) / 64;
    const int nb = (N + 1023) / 1024;

    prep_w<<<513, 256, 0, stream>>>(lin_w, msg_w1, msg_w2, att_w1, out_w1, out_w2,
                                    att_b1, wp, bias256);
    hipMemsetAsync(cnt, 0, (size_t)N * sizeof(int), stream);
    hist_k<<<1024, 256, 0, stream>>>(row, cnt, E);
    scan_a<<<nb, 1024, 0, stream>>>(cnt, off, btot, N);
    scan_b<<<1, 64, 0, stream>>>(btot, bexc, off, N, nb, E);
    scan_c<<<nb, 1024, 0, stream>>>(off, bexc, cnt, N);
    scatter_k<<<1024, 256, 0, stream>>>(row, col, edge_attr, edge_mask,
                                        cnt, rowS, colS, eamS, E);

    // x = h @ lin_w + lin_b                        (f32 out + bf16 copy)
    gemm_mfma<0, 8, 0, 2, 0><<<gb, 256, 0, stream>>>(h, wp, lin_b, nullptr, nullptr, nullptr,
                                                     x, 128, xbH, 128, N);
    // xr|xc = x @ att_w1[0:256] + [b1|0]           (split destinations)
    gemm_mfma<0, 16, 1, 1, 1><<<gb, 256, 0, stream>>>(xbH, wp + 3 * 16384, bias256, nullptr, nullptr, nullptr,
                                                      xrH, 128, xcH, 128, N);
    // att scalars for every edge (sorted order)
    att_edge<<<2048, 256, 0, stream>>>(xrH, xcH, rowS, colS, eamS,
                                       att_w1 + 256 * 128, att_w2, att_b2, catS, E);

    // xm = (LN(silu(x @ msg_w1 + msg_b1))) @ msg_w2 + msg_b2   (fused, bf16 out)
    gemm2_mfma<1, 0><<<gb, 256, 0, stream>>>(xbH, wp + 16384, msg_b1, msg_ln_g, msg_ln_b,
                                             wp + 2 * 16384, msg_b2, nullptr, nullptr,
                                             nullptr, xmH, N);

    // msg[r] = sum att * xm[col]
    accum_k<<<2048, 256, 0, stream>>>(xmH, off, catS, msg, N);

    // out = LN(x + (LN(silu(msg @ out_w1 + out_b1))) @ out_w2 + out_b2)  (fused, f32)
    gemm2_mfma<0, 3><<<gb, 256, 0, stream>>>(msg, wp + 5 * 16384, out_b1, out_ln_g, out_ln_b,
                                             wp + 6 * 16384, out_b2, ln_g, ln_b,
                                             x, (float*)d_out, N);
}

// Round 8
// 251.098 us; speedup vs baseline: 1.2682x; 1.1888x over previous
//
#include <hip/hip_runtime.h>

#define LN_EPS 1e-5f

typedef __attribute__((ext_vector_type(8))) short short8;
typedef __attribute__((ext_vector_type(4))) float f32x4;

// sigmoid via native exp + rcp (NO IEEE division -- v_div_* chain is ~10 VALU ops)
__device__ __forceinline__ float sigf(float x) {
    return __builtin_amdgcn_rcpf(1.0f + __expf(-x));
}

__device__ __forceinline__ unsigned short f2bf(float f) {
    unsigned u = __float_as_uint(f);
    return (unsigned short)((u + 0x7fffu + ((u >> 16) & 1u)) >> 16);
}
__device__ __forceinline__ unsigned f2bf2(float lo, float hi) {
    return (unsigned)f2bf(lo) | ((unsigned)f2bf(hi) << 16);
}
__device__ __forceinline__ void bf2f(unsigned u, float& lo, float& hi) {
    lo = __uint_as_float(u << 16);
    hi = __uint_as_float(u & 0xffff0000u);
}
__device__ __forceinline__ void bf8f(uint4 p, float* o) {
    bf2f(p.x, o[0], o[1]); bf2f(p.y, o[2], o[3]);
    bf2f(p.z, o[4], o[5]); bf2f(p.w, o[6], o[7]);
}
__device__ __forceinline__ float bf1f(unsigned short s) {
    return __uint_as_float(((unsigned)s) << 16);
}

// butterfly sum over each quad (lanes 4k..4k+3) via DPP quad_perm — no DS ops
__device__ __forceinline__ float quad_add_all(float x) {
    int v = __builtin_amdgcn_update_dpp(0, __float_as_int(x), 0xB1, 0xF, 0xF, true); // [1,0,3,2]
    x += __int_as_float(v);
    v = __builtin_amdgcn_update_dpp(0, __float_as_int(x), 0x4E, 0xF, 0xF, true);     // [2,3,0,1]
    x += __int_as_float(v);
    return x;
}

// ---- weight prep: f32 [128][128] row-major -> fragment-linear bf16 ----
__global__ __launch_bounds__(256)
void prep_w(const float* __restrict__ lin_w, const float* __restrict__ msg_w1,
            const float* __restrict__ msg_w2, const float* __restrict__ att_w1,
            const float* __restrict__ out_w1, const float* __restrict__ out_w2,
            const float* __restrict__ att_b1, unsigned short* __restrict__ wp,
            float* __restrict__ bias256)
{
    const int idx = blockIdx.x * 256 + threadIdx.x;
    if (idx < 8 * 16384) {
        const int m = idx >> 14, r = idx & 16383;
        const int k = r >> 7, n = r & 127;
        const float* src; int slot; int fnBase = 0;
        switch (m) {
            case 0: src = lin_w;  slot = 0; break;
            case 1: src = msg_w1; slot = 1; break;
            case 2: src = msg_w2; slot = 2; break;
            case 3: src = att_w1; slot = 3; break;
            case 4: src = att_w1 + 128 * 128; slot = 3; fnBase = 8; break;
            case 5: src = out_w1; slot = 5; break;
            default: src = out_w2; slot = 6; break;
        }
        const float v = src[k * 128 + n];
        const int fn = fnBase + (n >> 4);
        const int fk = k >> 5, kb = (k >> 3) & 3, j = k & 7;
        const size_t dst = (size_t)slot * 16384 + ((size_t)((fn * 4 + fk) * 64 + (n & 15) + 16 * kb)) * 8 + j;
        wp[dst] = f2bf(v);
    } else if (idx < 8 * 16384 + 256) {
        const int t = idx - 8 * 16384;
        bias256[t] = (t < 128) ? att_b1[t] : 0.f;
    }
}

// ---- A-fragment loaders (direct from row-major global, no LDS) ----
__device__ __forceinline__ short8 ldA_bf(const unsigned short* A, size_t row, int k0) {
    return *(const short8*)(A + row * 128 + k0);
}
__device__ __forceinline__ short8 ldA_f32(const float* A, size_t row, int k0) {
    const float* ap = A + row * 128 + k0;
    const float4 f0 = *(const float4*)ap;
    const float4 f1 = *(const float4*)(ap + 4);
    union { unsigned u[4]; short8 s; } v;
    v.u[0] = f2bf2(f0.x, f0.y); v.u[1] = f2bf2(f0.z, f0.w);
    v.u[2] = f2bf2(f1.x, f1.y); v.u[3] = f2bf2(f1.z, f1.w);
    return v.s;
}

// ---- barrier-free bf16 MFMA GEMM: bf16_out(A[N,128] @ W + bias) ----
// ABF: A bf16.  SPLIT (NFN=16): fn<8 -> C1, fn>=8 -> C2 (fn rebased).
template<int NFN, int ABF, int SPLIT>
__global__ __launch_bounds__(256, NFN == 8 ? 4 : 3)
void gemm_mfma(const void* __restrict__ Av, const unsigned short* __restrict__ Wp,
               const float* __restrict__ bias,
               unsigned short* __restrict__ C1, int ld1,
               unsigned short* __restrict__ C2, int ld2, int nrows)
{
    const int tid = threadIdx.x;
    const int w = tid >> 6, lane = tid & 63;
    const int r0 = blockIdx.x * 64;
    const int arow = r0 + w * 16 + (lane & 15);
    const size_t rowc = (arow < nrows) ? (size_t)arow : (size_t)(nrows - 1);
    const int kh = (lane >> 4) * 8;

    short8 a[4];
#pragma unroll
    for (int fk = 0; fk < 4; ++fk)
        a[fk] = ABF ? ldA_bf((const unsigned short*)Av, rowc, fk * 32 + kh)
                    : ldA_f32((const float*)Av, rowc, fk * 32 + kh);

    const short8* Bf = (const short8*)Wp;
    f32x4 acc[NFN];
#pragma unroll
    for (int fn = 0; fn < NFN; ++fn) acc[fn] = (f32x4){0.f, 0.f, 0.f, 0.f};
#pragma unroll
    for (int fk = 0; fk < 4; ++fk)
#pragma unroll
        for (int fn = 0; fn < NFN; ++fn)
            acc[fn] = __builtin_amdgcn_mfma_f32_16x16x32_bf16(a[fk], Bf[(fn * 4 + fk) * 64 + lane], acc[fn], 0, 0, 0);

    const int cn = lane & 15, rq = lane >> 4;
    float bv[NFN];
#pragma unroll
    for (int fn = 0; fn < NFN; ++fn) bv[fn] = bias ? bias[fn * 16 + cn] : 0.f;

#pragma unroll
    for (int reg = 0; reg < 4; ++reg) {
        const int gr = r0 + w * 16 + rq * 4 + reg;
        if (gr < nrows) {
#pragma unroll
            for (int fn = 0; fn < NFN; ++fn) {
                const float v = acc[fn][reg] + bv[fn];
                if (SPLIT) {
                    if (fn < 8) C1[(size_t)gr * ld1 + fn * 16 + cn] = f2bf(v);
                    else        C2[(size_t)gr * ld2 + (fn - 8) * 16 + cn] = f2bf(v);
                } else {
                    C1[(size_t)gr * ld1 + fn * 16 + cn] = f2bf(v);
                }
            }
        }
    }
}

// ---- fused double GEMM: C = epi2( LN(silu(A@W1+b1)) @ W2 + b2 ) ----
// A bf16. Stage-1 handoff per-wave via XOR-swizzled LDS (no barrier).
// EPI2 0: +b2, bf16 C.  EPI2 3: +b2+res(bf16) then LN(ln2), f32 C.
template<int EPI2>
__global__ __launch_bounds__(256, 4)
void gemm2_mfma(const unsigned short* __restrict__ Av,
                const unsigned short* __restrict__ Wp1, const float* __restrict__ b1,
                const float* __restrict__ ln1g, const float* __restrict__ ln1b,
                const unsigned short* __restrict__ Wp2, const float* __restrict__ b2,
                const float* __restrict__ ln2g, const float* __restrict__ ln2b,
                const unsigned short* __restrict__ resH, void* __restrict__ Cv, int nrows)
{
    __shared__ unsigned short hof[4 * 2048];   // 16 KiB, 4 KiB per wave
    const int tid = threadIdx.x;
    const int w = tid >> 6, lane = tid & 63;
    const int r0 = blockIdx.x * 64;
    const int arow = r0 + w * 16 + (lane & 15);
    const size_t rowc = (arow < nrows) ? (size_t)arow : (size_t)(nrows - 1);
    const int kh = (lane >> 4) * 8;
    const int cn = lane & 15, rq = lane >> 4;

    short8 a[4];
#pragma unroll
    for (int fk = 0; fk < 4; ++fk)
        a[fk] = ldA_bf(Av, rowc, fk * 32 + kh);

    const short8* B1f = (const short8*)Wp1;
    f32x4 acc[8];
#pragma unroll
    for (int fn = 0; fn < 8; ++fn) acc[fn] = (f32x4){0.f, 0.f, 0.f, 0.f};
#pragma unroll
    for (int fk = 0; fk < 4; ++fk)
#pragma unroll
        for (int fn = 0; fn < 8; ++fn)
            acc[fn] = __builtin_amdgcn_mfma_f32_16x16x32_bf16(a[fk], B1f[(fn * 4 + fk) * 64 + lane], acc[fn], 0, 0, 0);

    // epilogue-1: silu + LN -> wave-private swizzled LDS handoff
    unsigned short* hw = hof + w * 2048;
    {
        float bv[8], gv[8], bbv[8];
#pragma unroll
        for (int fn = 0; fn < 8; ++fn) {
            bv[fn] = b1[fn * 16 + cn]; gv[fn] = ln1g[fn * 16 + cn]; bbv[fn] = ln1b[fn * 16 + cn];
        }
#pragma unroll
        for (int reg = 0; reg < 4; ++reg) {
            float val[8];
            float sum = 0.f, sq = 0.f;
#pragma unroll
            for (int fn = 0; fn < 8; ++fn) {
                float v = acc[fn][reg] + bv[fn];
                v = v * sigf(v);
                val[fn] = v; sum += v; sq += v * v;
            }
#pragma unroll
            for (int m = 1; m < 16; m <<= 1) { sum += __shfl_xor(sum, m); sq += __shfl_xor(sq, m); }
            const float mean = sum * (1.f / 128.f);
            const float var = sq * (1.f / 128.f) - mean * mean;
            const float rstd = rsqrtf(var + LN_EPS);
            const int row16 = rq * 4 + reg;
            const int sw = (row16 & 7) << 3;           // XOR swizzle (ushort units)
#pragma unroll
            for (int fn = 0; fn < 8; ++fn) {
                const float o = (val[fn] - mean) * rstd * gv[fn] + bbv[fn];
                hw[row16 * 128 + ((fn * 16 + cn) ^ sw)] = f2bf(o);
            }
        }
    }

    // stage-2 A frags from handoff (intra-wave lgkmcnt ordering only)
    short8 a2[4];
    {
        const int row16 = lane & 15;
        const int sw = (row16 & 7) << 3;
#pragma unroll
        for (int fk = 0; fk < 4; ++fk)
            a2[fk] = *(const short8*)(hw + row16 * 128 + ((fk * 32 + kh) ^ sw));
    }

    const short8* B2f = (const short8*)Wp2;
    f32x4 acc2[8];
#pragma unroll
    for (int fn = 0; fn < 8; ++fn) acc2[fn] = (f32x4){0.f, 0.f, 0.f, 0.f};
#pragma unroll
    for (int fk = 0; fk < 4; ++fk)
#pragma unroll
        for (int fn = 0; fn < 8; ++fn)
            acc2[fn] = __builtin_amdgcn_mfma_f32_16x16x32_bf16(a2[fk], B2f[(fn * 4 + fk) * 64 + lane], acc2[fn], 0, 0, 0);

    // epilogue-2
    float bv2[8];
#pragma unroll
    for (int fn = 0; fn < 8; ++fn) bv2[fn] = b2[fn * 16 + cn];

    if (EPI2 == 0) {
        unsigned short* Ch = (unsigned short*)Cv;
#pragma unroll
        for (int reg = 0; reg < 4; ++reg) {
            const int gr = r0 + w * 16 + rq * 4 + reg;
            if (gr < nrows) {
#pragma unroll
                for (int fn = 0; fn < 8; ++fn)
                    Ch[(size_t)gr * 128 + fn * 16 + cn] = f2bf(acc2[fn][reg] + bv2[fn]);
            }
        }
    } else {
        float* Cf = (float*)Cv;
        float gv[8], bbv[8];
#pragma unroll
        for (int fn = 0; fn < 8; ++fn) { gv[fn] = ln2g[fn * 16 + cn]; bbv[fn] = ln2b[fn * 16 + cn]; }
#pragma unroll
        for (int reg = 0; reg < 4; ++reg) {
            const int gr = r0 + w * 16 + rq * 4 + reg;
            const int grc = gr < nrows ? gr : nrows - 1;
            float val[8];
            float sum = 0.f, sq = 0.f;
#pragma unroll
            for (int fn = 0; fn < 8; ++fn) {
                float v = acc2[fn][reg] + bv2[fn] + bf1f(resH[(size_t)grc * 128 + fn * 16 + cn]);
                val[fn] = v; sum += v; sq += v * v;
            }
#pragma unroll
            for (int m = 1; m < 16; m <<= 1) { sum += __shfl_xor(sum, m); sq += __shfl_xor(sq, m); }
            const float mean = sum * (1.f / 128.f);
            const float var = sq * (1.f / 128.f) - mean * mean;
            const float rstd = rsqrtf(var + LN_EPS);
            if (gr < nrows) {
#pragma unroll
                for (int fn = 0; fn < 8; ++fn)
                    Cf[(size_t)gr * 128 + fn * 16 + cn] = (val[fn] - mean) * rstd * gv[fn] + bbv[fn];
            }
        }
    }
}

// ---- counting sort of edges by row ----

__global__ __launch_bounds__(256)
void hist_k(const int* __restrict__ row, int* __restrict__ cnt, int E)
{
    for (int e = blockIdx.x * blockDim.x + threadIdx.x; e < E; e += gridDim.x * blockDim.x)
        atomicAdd(&cnt[row[e]], 1);
}

__global__ __launch_bounds__(1024)
void scan_a(const int* __restrict__ cnt, int* __restrict__ off,
            int* __restrict__ btot, int n)
{
    __shared__ int wsum[16];
    const int tid = threadIdx.x, lane = tid & 63, wv = tid >> 6;
    const int i = blockIdx.x * 1024 + tid;
    const int v = (i < n) ? cnt[i] : 0;
    int incl = v;
#pragma unroll
    for (int d = 1; d < 64; d <<= 1) { int t = __shfl_up(incl, d); if (lane >= d) incl += t; }
    if (lane == 63) wsum[wv] = incl;
    __syncthreads();
    if (tid == 0) {
        int run = 0;
        for (int ww = 0; ww < 16; ++ww) { int t = wsum[ww]; wsum[ww] = run; run += t; }
    }
    __syncthreads();
    if (i < n) off[i] = wsum[wv] + incl - v;
    if (tid == 1023) btot[blockIdx.x] = wsum[15] + incl;
}

__global__ __launch_bounds__(64)
void scan_b(int* __restrict__ btot, int* __restrict__ bexc,
            int* __restrict__ off, int n, int nb, int E)
{
    const int t = threadIdx.x;
    const int v = (t < nb) ? btot[t] : 0;
    int incl = v;
#pragma unroll
    for (int d = 1; d < 64; d <<= 1) { int u = __shfl_up(incl, d); if (t >= d) incl += u; }
    if (t < nb) bexc[t] = incl - v;
    if (t == 0) off[n] = E;
}

__global__ __launch_bounds__(1024)
void scan_c(int* __restrict__ off, const int* __restrict__ bexc,
            int* __restrict__ cursor, int n)
{
    const int i = blockIdx.x * 1024 + threadIdx.x;
    if (i < n) {
        const int o = off[i] + bexc[blockIdx.x];
        off[i] = o;
        cursor[i] = o;
    }
}

__global__ __launch_bounds__(256)
void scatter_k(const int* __restrict__ row, const int* __restrict__ col,
               const float* __restrict__ ea, const float* __restrict__ em,
               int* __restrict__ cursor, int* __restrict__ rowS,
               int* __restrict__ colS, float2* __restrict__ eamS, int E)
{
    for (int e = blockIdx.x * blockDim.x + threadIdx.x; e < E; e += gridDim.x * blockDim.x) {
        const int r = row[e];
        const int pos = atomicAdd(&cursor[r], 1);
        rowS[pos] = r;
        colS[pos] = col[e];
        eamS[pos] = make_float2(ea[e], em[e]);
    }
}

// ---- edge-parallel attention, quad-per-edge ----
__global__ __launch_bounds__(256, 4)
void att_edge(const unsigned short* __restrict__ xrH,
              const unsigned short* __restrict__ xcH,
              const int* __restrict__ rowS, const int* __restrict__ colS,
              const float2* __restrict__ eamS, const float* __restrict__ we_,
              const float* __restrict__ w2_, const float* __restrict__ b2p,
              uint2* __restrict__ catS, int E)
{
    const int lane = threadIdx.x & 63;
    const int q = lane & 3;
    const int gwid = (blockIdx.x * blockDim.x + threadIdx.x) >> 6;
    const int nw = (gridDim.x * blockDim.x) >> 6;

    float we[32], w2[32];
#pragma unroll
    for (int ch = 0; ch < 4; ++ch) {
        const float4 a0 = ((const float4*)we_)[ch * 8 + q * 2];
        const float4 a1 = ((const float4*)we_)[ch * 8 + q * 2 + 1];
        we[ch * 8 + 0] = a0.x; we[ch * 8 + 1] = a0.y; we[ch * 8 + 2] = a0.z; we[ch * 8 + 3] = a0.w;
        we[ch * 8 + 4] = a1.x; we[ch * 8 + 5] = a1.y; we[ch * 8 + 6] = a1.z; we[ch * 8 + 7] = a1.w;
        const float4 c0 = ((const float4*)w2_)[ch * 8 + q * 2];
        const float4 c1 = ((const float4*)w2_)[ch * 8 + q * 2 + 1];
        w2[ch * 8 + 0] = c0.x; w2[ch * 8 + 1] = c0.y; w2[ch * 8 + 2] = c0.z; w2[ch * 8 + 3] = c0.w;
        w2[ch * 8 + 4] = c1.x; w2[ch * 8 + 5] = c1.y; w2[ch * 8 + 6] = c1.z; w2[ch * 8 + 7] = c1.w;
    }
    const float b2 = *b2p;

    for (int base = gwid * 16; base < E; base += nw * 16) {
        const int e = base + (lane >> 2);
        const bool valid = e < E;
        const int ec = valid ? e : E - 1;
        const int r = rowS[ec], c = colS[ec];
        const float2 eam = eamS[ec];
        const unsigned short* xr = xrH + (size_t)r * 128;
        const unsigned short* xc = xcH + (size_t)c * 128;
        float p = 0.f;
#pragma unroll
        for (int ch = 0; ch < 4; ++ch) {
            const uint4 pa = *(const uint4*)(xr + ch * 32 + q * 8);
            const uint4 pb = *(const uint4*)(xc + ch * 32 + q * 8);
            float xa[8], xb[8];
            bf8f(pa, xa); bf8f(pb, xb);
#pragma unroll
            for (int i = 0; i < 8; ++i) {
                const float t = xa[i] + xb[i] + eam.x * we[ch * 8 + i];
                p += t * sigf(t) * w2[ch * 8 + i];
            }
        }
        p = quad_add_all(p);
        const float att = sigf(p + b2) * eam.y;
        if (valid && q == 0) catS[e] = make_uint2((unsigned)c, __float_as_uint(att));
    }
}

// ---- row accumulation: msgH[r] = bf16( sum att * xm[col] ) ----
__global__ __launch_bounds__(256)
void accum_k(const unsigned short* __restrict__ xmH, const int* __restrict__ off,
             const uint2* __restrict__ catS, unsigned short* __restrict__ msgH, int N)
{
    const int lane = threadIdx.x & 63;
    const int g = lane >> 4, l = lane & 15;
    const int gwid = (blockIdx.x * blockDim.x + threadIdx.x) >> 6;
    const int nw = (gridDim.x * blockDim.x) >> 6;
    const uint4* xm4 = (const uint4*)xmH;

    for (int wid = gwid; wid < N; wid += nw) {
        int j0 = off[wid];
        const int jend = off[wid + 1];
        float acc[8] = {0.f, 0.f, 0.f, 0.f, 0.f, 0.f, 0.f, 0.f};

        // 16 edges in flight per iteration (4 per group)
        for (; j0 + 16 <= jend; j0 += 16) {
            uint2 ca[4]; uint4 pk[4];
#pragma unroll
            for (int u = 0; u < 4; ++u) ca[u] = catS[j0 + u * 4 + g];
#pragma unroll
            for (int u = 0; u < 4; ++u) pk[u] = xm4[(size_t)ca[u].x * 16 + l];
#pragma unroll
            for (int u = 0; u < 4; ++u) {
                const float att = __uint_as_float(ca[u].y);
                float xm[8];
                bf8f(pk[u], xm);
#pragma unroll
                for (int i = 0; i < 8; ++i) acc[i] = fmaf(att, xm[i], acc[i]);
            }
        }
        for (; j0 + 8 <= jend; j0 += 8) {
            const uint2 caA = catS[j0 + g];
            const uint2 caB = catS[j0 + 4 + g];
            const uint4 pA = xm4[(size_t)caA.x * 16 + l];
            const uint4 pB = xm4[(size_t)caB.x * 16 + l];
            const float attA = __uint_as_float(caA.y);
            const float attB = __uint_as_float(caB.y);
            float xmA[8], xmB[8];
            bf8f(pA, xmA); bf8f(pB, xmB);
#pragma unroll
            for (int i = 0; i < 8; ++i)
                acc[i] = fmaf(attB, xmB[i], fmaf(attA, xmA[i], acc[i]));
        }
        for (; j0 < jend; j0 += 4) {
            const int je = j0 + g;
            const bool valid = je < jend;
            const int jc = valid ? je : jend - 1;
            const uint2 ca = catS[jc];
            const uint4 p = xm4[(size_t)ca.x * 16 + l];
            const float att = valid ? __uint_as_float(ca.y) : 0.f;
            float xm[8];
            bf8f(p, xm);
#pragma unroll
            for (int i = 0; i < 8; ++i) acc[i] = fmaf(att, xm[i], acc[i]);
        }

#pragma unroll
        for (int i = 0; i < 8; ++i) {
            acc[i] += __shfl_xor(acc[i], 16);
            acc[i] += __shfl_xor(acc[i], 32);
        }
        if (g == 0) {
            uint4 pk;
            pk.x = f2bf2(acc[0], acc[1]); pk.y = f2bf2(acc[2], acc[3]);
            pk.z = f2bf2(acc[4], acc[5]); pk.w = f2bf2(acc[6], acc[7]);
            ((uint4*)msgH)[(size_t)wid * 16 + l] = pk;
        }
    }
}

extern "C" void kernel_launch(void* const* d_in, const int* in_sizes, int n_in,
                              void* d_out, int out_size, void* d_ws, size_t ws_size,
                              hipStream_t stream)
{
    const float* h        = (const float*)d_in[0];
    const float* edge_attr= (const float*)d_in[1];
    const int*   row      = (const int*)d_in[2];
    const int*   col      = (const int*)d_in[3];
    const float* edge_mask= (const float*)d_in[5];
    const float* lin_w    = (const float*)d_in[6];
    const float* lin_b    = (const float*)d_in[7];
    const float* msg_w1   = (const float*)d_in[8];
    const float* msg_b1   = (const float*)d_in[9];
    const float* msg_ln_g = (const float*)d_in[10];
    const float* msg_ln_b = (const float*)d_in[11];
    const float* msg_w2   = (const float*)d_in[12];
    const float* msg_b2   = (const float*)d_in[13];
    const float* att_w1   = (const float*)d_in[14];
    const float* att_b1   = (const float*)d_in[15];
    const float* att_w2   = (const float*)d_in[16];
    const float* att_b2   = (const float*)d_in[17];
    const float* out_w1   = (const float*)d_in[18];
    const float* out_b1   = (const float*)d_in[19];
    const float* out_ln_g = (const float*)d_in[20];
    const float* out_ln_b = (const float*)d_in[21];
    const float* out_w2   = (const float*)d_in[22];
    const float* out_b2   = (const float*)d_in[23];
    const float* ln_g     = (const float*)d_in[24];
    const float* ln_b     = (const float*)d_in[25];

    const int N = in_sizes[0] / 128;
    const int E = in_sizes[2];
    const size_t NF = (size_t)N * 128;

    unsigned short* xbH  = (unsigned short*)d_ws;       // bf16 [N][128] x
    unsigned short* xrH  = xbH + NF;                    // bf16 [N][128]
    unsigned short* xcH  = xrH + NF;                    // bf16 [N][128]
    unsigned short* xmH  = xcH + NF;                    // bf16 [N][128]
    unsigned short* msgH = xmH + NF;                    // bf16 [N][128]
    int*    cnt   = (int*)(msgH + NF);                  // N (reused as cursor)
    int*    off   = cnt + N;                            // N+1 (alloc N+8)
    int*    btot  = off + N + 8;                        // 64
    int*    bexc  = btot + 64;                          // 64
    int*    rowS  = bexc + 64;                          // E
    int*    colS  = rowS + E;                           // E
    float2* eamS  = (float2*)(colS + E);                // E
    uint2*  catS  = (uint2*)(eamS + E);                 // E
    unsigned short* wp = (unsigned short*)(catS + E);   // 8*16384 bf16
    float* bias256 = (float*)(wp + 8 * 16384);

    const int gb = (N + 63) / 64;
    const int nb = (N + 1023) / 1024;

    prep_w<<<513, 256, 0, stream>>>(lin_w, msg_w1, msg_w2, att_w1, out_w1, out_w2,
                                    att_b1, wp, bias256);
    hipMemsetAsync(cnt, 0, (size_t)N * sizeof(int), stream);
    hist_k<<<1024, 256, 0, stream>>>(row, cnt, E);
    scan_a<<<nb, 1024, 0, stream>>>(cnt, off, btot, N);
    scan_b<<<1, 64, 0, stream>>>(btot, bexc, off, N, nb, E);
    scan_c<<<nb, 1024, 0, stream>>>(off, bexc, cnt, N);
    scatter_k<<<1024, 256, 0, stream>>>(row, col, edge_attr, edge_mask,
                                        cnt, rowS, colS, eamS, E);

    // x = bf16(h @ lin_w + lin_b)
    gemm_mfma<8, 0, 0><<<gb, 256, 0, stream>>>(h, wp, lin_b, xbH, 128, nullptr, 0, N);
    // xr|xc = x @ att_w1[0:256] + [b1|0]           (split destinations)
    gemm_mfma<16, 1, 1><<<gb, 256, 0, stream>>>(xbH, wp + 3 * 16384, bias256, xrH, 128, xcH, 128, N);
    // att scalars for every edge (sorted order)
    att_edge<<<2048, 256, 0, stream>>>(xrH, xcH, rowS, colS, eamS,
                                       att_w1 + 256 * 128, att_w2, att_b2, catS, E);

    // xm = (LN(silu(x @ msg_w1 + msg_b1))) @ msg_w2 + msg_b2   (fused, bf16)
    gemm2_mfma<0><<<gb, 256, 0, stream>>>(xbH, wp + 16384, msg_b1, msg_ln_g, msg_ln_b,
                                          wp + 2 * 16384, msg_b2, nullptr, nullptr,
                                          nullptr, xmH, N);

    // msg[r] = sum att * xm[col]  (bf16 out)
    accum_k<<<2048, 256, 0, stream>>>(xmH, off, catS, msgH, N);

    // out = LN(x + (LN(silu(msg @ out_w1 + out_b1))) @ out_w2 + out_b2)  (fused, f32)
    gemm2_mfma<3><<<gb, 256, 0, stream>>>(msgH, wp + 5 * 16384, out_b1, out_ln_g, out_ln_b,
                                          wp + 6 * 16384, out_b2, ln_g, ln_b,
                                          xbH, (float*)d_out, N);
}

// Round 9
// 249.053 us; speedup vs baseline: 1.2786x; 1.0082x over previous
//
#include <hip/hip_runtime.h>

#define LN_EPS 1e-5f

typedef __attribute__((ext_vector_type(8))) short short8;
typedef __attribute__((ext_vector_type(4))) float f32x4;

// sigmoid via native exp + rcp (NO IEEE division -- v_div_* chain is ~10 VALU ops)
__device__ __forceinline__ float sigf(float x) {
    return __builtin_amdgcn_rcpf(1.0f + __expf(-x));
}

__device__ __forceinline__ unsigned short f2bf(float f) {
    unsigned u = __float_as_uint(f);
    return (unsigned short)((u + 0x7fffu + ((u >> 16) & 1u)) >> 16);
}
__device__ __forceinline__ unsigned f2bf2(float lo, float hi) {
    return (unsigned)f2bf(lo) | ((unsigned)f2bf(hi) << 16);
}
__device__ __forceinline__ void bf2f(unsigned u, float& lo, float& hi) {
    lo = __uint_as_float(u << 16);
    hi = __uint_as_float(u & 0xffff0000u);
}
__device__ __forceinline__ void bf8f(uint4 p, float* o) {
    bf2f(p.x, o[0], o[1]); bf2f(p.y, o[2], o[3]);
    bf2f(p.z, o[4], o[5]); bf2f(p.w, o[6], o[7]);
}
__device__ __forceinline__ float bf1f(unsigned short s) {
    return __uint_as_float(((unsigned)s) << 16);
}

// butterfly sum over each quad (lanes 4k..4k+3) via DPP quad_perm — no DS ops
__device__ __forceinline__ float quad_add_all(float x) {
    int v = __builtin_amdgcn_update_dpp(0, __float_as_int(x), 0xB1, 0xF, 0xF, true); // [1,0,3,2]
    x += __int_as_float(v);
    v = __builtin_amdgcn_update_dpp(0, __float_as_int(x), 0x4E, 0xF, 0xF, true);     // [2,3,0,1]
    x += __int_as_float(v);
    return x;
}

// ---- weight prep: f32 [128][128] row-major -> fragment-linear bf16 ----
__global__ __launch_bounds__(256)
void prep_w(const float* __restrict__ lin_w, const float* __restrict__ msg_w1,
            const float* __restrict__ msg_w2, const float* __restrict__ att_w1,
            const float* __restrict__ out_w1, const float* __restrict__ out_w2,
            const float* __restrict__ att_b1, unsigned short* __restrict__ wp,
            float* __restrict__ bias256)
{
    const int idx = blockIdx.x * 256 + threadIdx.x;
    if (idx < 8 * 16384) {
        const int m = idx >> 14, r = idx & 16383;
        const int k = r >> 7, n = r & 127;
        const float* src; int slot; int fnBase = 0;
        switch (m) {
            case 0: src = lin_w;  slot = 0; break;
            case 1: src = msg_w1; slot = 1; break;
            case 2: src = msg_w2; slot = 2; break;
            case 3: src = att_w1; slot = 3; break;
            case 4: src = att_w1 + 128 * 128; slot = 3; fnBase = 8; break;
            case 5: src = out_w1; slot = 5; break;
            default: src = out_w2; slot = 6; break;
        }
        const float v = src[k * 128 + n];
        const int fn = fnBase + (n >> 4);
        const int fk = k >> 5, kb = (k >> 3) & 3, j = k & 7;
        const size_t dst = (size_t)slot * 16384 + ((size_t)((fn * 4 + fk) * 64 + (n & 15) + 16 * kb)) * 8 + j;
        wp[dst] = f2bf(v);
    } else if (idx < 8 * 16384 + 256) {
        const int t = idx - 8 * 16384;
        bias256[t] = (t < 128) ? att_b1[t] : 0.f;
    }
}

// ---- A-fragment loaders (direct from row-major global, no LDS) ----
__device__ __forceinline__ short8 ldA_bf(const unsigned short* A, size_t row, int k0) {
    return *(const short8*)(A + row * 128 + k0);
}
__device__ __forceinline__ short8 ldA_f32(const float* A, size_t row, int k0) {
    const float* ap = A + row * 128 + k0;
    const float4 f0 = *(const float4*)ap;
    const float4 f1 = *(const float4*)(ap + 4);
    union { unsigned u[4]; short8 s; } v;
    v.u[0] = f2bf2(f0.x, f0.y); v.u[1] = f2bf2(f0.z, f0.w);
    v.u[2] = f2bf2(f1.x, f1.y); v.u[3] = f2bf2(f1.z, f1.w);
    return v.s;
}

// ---- barrier-free bf16 MFMA GEMM: bf16_out(A[N,128] @ W + bias) ----
// ABF: A bf16.  SPLIT (NFN=16): fn<8 -> C1, fn>=8 -> C2 (fn rebased).
template<int NFN, int ABF, int SPLIT>
__global__ __launch_bounds__(256, NFN == 8 ? 4 : 3)
void gemm_mfma(const void* __restrict__ Av, const unsigned short* __restrict__ Wp,
               const float* __restrict__ bias,
               unsigned short* __restrict__ C1, int ld1,
               unsigned short* __restrict__ C2, int ld2, int nrows)
{
    const int tid = threadIdx.x;
    const int w = tid >> 6, lane = tid & 63;
    const int r0 = blockIdx.x * 64;
    const int arow = r0 + w * 16 + (lane & 15);
    const size_t rowc = (arow < nrows) ? (size_t)arow : (size_t)(nrows - 1);
    const int kh = (lane >> 4) * 8;

    short8 a[4];
#pragma unroll
    for (int fk = 0; fk < 4; ++fk)
        a[fk] = ABF ? ldA_bf((const unsigned short*)Av, rowc, fk * 32 + kh)
                    : ldA_f32((const float*)Av, rowc, fk * 32 + kh);

    const short8* Bf = (const short8*)Wp;
    f32x4 acc[NFN];
#pragma unroll
    for (int fn = 0; fn < NFN; ++fn) acc[fn] = (f32x4){0.f, 0.f, 0.f, 0.f};
#pragma unroll
    for (int fk = 0; fk < 4; ++fk)
#pragma unroll
        for (int fn = 0; fn < NFN; ++fn)
            acc[fn] = __builtin_amdgcn_mfma_f32_16x16x32_bf16(a[fk], Bf[(fn * 4 + fk) * 64 + lane], acc[fn], 0, 0, 0);

    const int cn = lane & 15, rq = lane >> 4;
    float bv[NFN];
#pragma unroll
    for (int fn = 0; fn < NFN; ++fn) bv[fn] = bias ? bias[fn * 16 + cn] : 0.f;

#pragma unroll
    for (int reg = 0; reg < 4; ++reg) {
        const int gr = r0 + w * 16 + rq * 4 + reg;
        if (gr < nrows) {
#pragma unroll
            for (int fn = 0; fn < NFN; ++fn) {
                const float v = acc[fn][reg] + bv[fn];
                if (SPLIT) {
                    if (fn < 8) C1[(size_t)gr * ld1 + fn * 16 + cn] = f2bf(v);
                    else        C2[(size_t)gr * ld2 + (fn - 8) * 16 + cn] = f2bf(v);
                } else {
                    C1[(size_t)gr * ld1 + fn * 16 + cn] = f2bf(v);
                }
            }
        }
    }
}

// ---- fused double GEMM: C = epi2( LN(silu(A@W1+b1)) @ W2 + b2 ) ----
// A bf16. Stage-1 handoff per-wave via XOR-swizzled LDS (no barrier).
// EPI2 0: +b2, bf16 C.  EPI2 3: +b2+res(bf16) then LN(ln2), f32 C.
template<int EPI2>
__global__ __launch_bounds__(256, 4)
void gemm2_mfma(const unsigned short* __restrict__ Av,
                const unsigned short* __restrict__ Wp1, const float* __restrict__ b1,
                const float* __restrict__ ln1g, const float* __restrict__ ln1b,
                const unsigned short* __restrict__ Wp2, const float* __restrict__ b2,
                const float* __restrict__ ln2g, const float* __restrict__ ln2b,
                const unsigned short* __restrict__ resH, void* __restrict__ Cv, int nrows)
{
    __shared__ unsigned short hof[4 * 2048];   // 16 KiB, 4 KiB per wave
    const int tid = threadIdx.x;
    const int w = tid >> 6, lane = tid & 63;
    const int r0 = blockIdx.x * 64;
    const int arow = r0 + w * 16 + (lane & 15);
    const size_t rowc = (arow < nrows) ? (size_t)arow : (size_t)(nrows - 1);
    const int kh = (lane >> 4) * 8;
    const int cn = lane & 15, rq = lane >> 4;

    short8 a[4];
#pragma unroll
    for (int fk = 0; fk < 4; ++fk)
        a[fk] = ldA_bf(Av, rowc, fk * 32 + kh);

    const short8* B1f = (const short8*)Wp1;
    f32x4 acc[8];
#pragma unroll
    for (int fn = 0; fn < 8; ++fn) acc[fn] = (f32x4){0.f, 0.f, 0.f, 0.f};
#pragma unroll
    for (int fk = 0; fk < 4; ++fk)
#pragma unroll
        for (int fn = 0; fn < 8; ++fn)
            acc[fn] = __builtin_amdgcn_mfma_f32_16x16x32_bf16(a[fk], B1f[(fn * 4 + fk) * 64 + lane], acc[fn], 0, 0, 0);

    // epilogue-1: silu + LN -> wave-private swizzled LDS handoff
    unsigned short* hw = hof + w * 2048;
    {
        float bv[8], gv[8], bbv[8];
#pragma unroll
        for (int fn = 0; fn < 8; ++fn) {
            bv[fn] = b1[fn * 16 + cn]; gv[fn] = ln1g[fn * 16 + cn]; bbv[fn] = ln1b[fn * 16 + cn];
        }
#pragma unroll
        for (int reg = 0; reg < 4; ++reg) {
            float val[8];
            float sum = 0.f, sq = 0.f;
#pragma unroll
            for (int fn = 0; fn < 8; ++fn) {
                float v = acc[fn][reg] + bv[fn];
                v = v * sigf(v);
                val[fn] = v; sum += v; sq += v * v;
            }
#pragma unroll
            for (int m = 1; m < 16; m <<= 1) { sum += __shfl_xor(sum, m); sq += __shfl_xor(sq, m); }
            const float mean = sum * (1.f / 128.f);
            const float var = sq * (1.f / 128.f) - mean * mean;
            const float rstd = rsqrtf(var + LN_EPS);
            const int row16 = rq * 4 + reg;
            const int sw = (row16 & 7) << 3;           // XOR swizzle (ushort units)
#pragma unroll
            for (int fn = 0; fn < 8; ++fn) {
                const float o = (val[fn] - mean) * rstd * gv[fn] + bbv[fn];
                hw[row16 * 128 + ((fn * 16 + cn) ^ sw)] = f2bf(o);
            }
        }
    }

    // stage-2 A frags from handoff (intra-wave lgkmcnt ordering only)
    short8 a2[4];
    {
        const int row16 = lane & 15;
        const int sw = (row16 & 7) << 3;
#pragma unroll
        for (int fk = 0; fk < 4; ++fk)
            a2[fk] = *(const short8*)(hw + row16 * 128 + ((fk * 32 + kh) ^ sw));
    }

    const short8* B2f = (const short8*)Wp2;
    f32x4 acc2[8];
#pragma unroll
    for (int fn = 0; fn < 8; ++fn) acc2[fn] = (f32x4){0.f, 0.f, 0.f, 0.f};
#pragma unroll
    for (int fk = 0; fk < 4; ++fk)
#pragma unroll
        for (int fn = 0; fn < 8; ++fn)
            acc2[fn] = __builtin_amdgcn_mfma_f32_16x16x32_bf16(a2[fk], B2f[(fn * 4 + fk) * 64 + lane], acc2[fn], 0, 0, 0);

    // epilogue-2
    float bv2[8];
#pragma unroll
    for (int fn = 0; fn < 8; ++fn) bv2[fn] = b2[fn * 16 + cn];

    if (EPI2 == 0) {
        unsigned short* Ch = (unsigned short*)Cv;
#pragma unroll
        for (int reg = 0; reg < 4; ++reg) {
            const int gr = r0 + w * 16 + rq * 4 + reg;
            if (gr < nrows) {
#pragma unroll
                for (int fn = 0; fn < 8; ++fn)
                    Ch[(size_t)gr * 128 + fn * 16 + cn] = f2bf(acc2[fn][reg] + bv2[fn]);
            }
        }
    } else {
        float* Cf = (float*)Cv;
        float gv[8], bbv[8];
#pragma unroll
        for (int fn = 0; fn < 8; ++fn) { gv[fn] = ln2g[fn * 16 + cn]; bbv[fn] = ln2b[fn * 16 + cn]; }
#pragma unroll
        for (int reg = 0; reg < 4; ++reg) {
            const int gr = r0 + w * 16 + rq * 4 + reg;
            const int grc = gr < nrows ? gr : nrows - 1;
            float val[8];
            float sum = 0.f, sq = 0.f;
#pragma unroll
            for (int fn = 0; fn < 8; ++fn) {
                float v = acc2[fn][reg] + bv2[fn] + bf1f(resH[(size_t)grc * 128 + fn * 16 + cn]);
                val[fn] = v; sum += v; sq += v * v;
            }
#pragma unroll
            for (int m = 1; m < 16; m <<= 1) { sum += __shfl_xor(sum, m); sq += __shfl_xor(sq, m); }
            const float mean = sum * (1.f / 128.f);
            const float var = sq * (1.f / 128.f) - mean * mean;
            const float rstd = rsqrtf(var + LN_EPS);
            if (gr < nrows) {
#pragma unroll
                for (int fn = 0; fn < 8; ++fn)
                    Cf[(size_t)gr * 128 + fn * 16 + cn] = (val[fn] - mean) * rstd * gv[fn] + bbv[fn];
            }
        }
    }
}

// ---- counting sort of edges by row ----

__global__ __launch_bounds__(256)
void hist_k(const int* __restrict__ row, int* __restrict__ cnt, int E)
{
    for (int e = blockIdx.x * blockDim.x + threadIdx.x; e < E; e += gridDim.x * blockDim.x)
        atomicAdd(&cnt[row[e]], 1);
}

__global__ __launch_bounds__(1024)
void scan_a(const int* __restrict__ cnt, int* __restrict__ off,
            int* __restrict__ btot, int n)
{
    __shared__ int wsum[16];
    const int tid = threadIdx.x, lane = tid & 63, wv = tid >> 6;
    const int i = blockIdx.x * 1024 + tid;
    const int v = (i < n) ? cnt[i] : 0;
    int incl = v;
#pragma unroll
    for (int d = 1; d < 64; d <<= 1) { int t = __shfl_up(incl, d); if (lane >= d) incl += t; }
    if (lane == 63) wsum[wv] = incl;
    __syncthreads();
    if (tid == 0) {
        int run = 0;
        for (int ww = 0; ww < 16; ++ww) { int t = wsum[ww]; wsum[ww] = run; run += t; }
    }
    __syncthreads();
    if (i < n) off[i] = wsum[wv] + incl - v;
    if (tid == 1023) btot[blockIdx.x] = wsum[15] + incl;
}

__global__ __launch_bounds__(64)
void scan_b(int* __restrict__ btot, int* __restrict__ bexc,
            int* __restrict__ off, int n, int nb, int E)
{
    const int t = threadIdx.x;
    const int v = (t < nb) ? btot[t] : 0;
    int incl = v;
#pragma unroll
    for (int d = 1; d < 64; d <<= 1) { int u = __shfl_up(incl, d); if (t >= d) incl += u; }
    if (t < nb) bexc[t] = incl - v;
    if (t == 0) off[n] = E;
}

__global__ __launch_bounds__(1024)
void scan_c(int* __restrict__ off, const int* __restrict__ bexc,
            int* __restrict__ cursor, int n)
{
    const int i = blockIdx.x * 1024 + threadIdx.x;
    if (i < n) {
        const int o = off[i] + bexc[blockIdx.x];
        off[i] = o;
        cursor[i] = o;
    }
}

// ---- scatter: one 16B record per edge, 4-deep ILP ----
__global__ __launch_bounds__(256)
void scatter_k(const int* __restrict__ row, const int* __restrict__ col,
               const float* __restrict__ ea, const float* __restrict__ em,
               int* __restrict__ cursor, uint4* __restrict__ erec, int E)
{
    const int tid = blockIdx.x * blockDim.x + threadIdx.x;
    const int stride = gridDim.x * blockDim.x;
    for (int e0 = tid; e0 < E; e0 += stride * 4) {
        uint4 rec[4]; int pos[4]; bool val[4];
#pragma unroll
        for (int u = 0; u < 4; ++u) {
            const int e = e0 + u * stride;
            val[u] = e < E;
            const int ec = val[u] ? e : 0;
            rec[u].x = (unsigned)row[ec];
            rec[u].y = (unsigned)col[ec];
            rec[u].z = __float_as_uint(ea[ec]);
            rec[u].w = __float_as_uint(em[ec]);
        }
#pragma unroll
        for (int u = 0; u < 4; ++u)
            if (val[u]) pos[u] = atomicAdd(&cursor[rec[u].x], 1);
#pragma unroll
        for (int u = 0; u < 4; ++u)
            if (val[u]) erec[pos[u]] = rec[u];
    }
}

// ---- edge-parallel attention, quad-per-edge; reads one uint4 record/edge ----
__global__ __launch_bounds__(256, 4)
void att_edge(const unsigned short* __restrict__ xrH,
              const unsigned short* __restrict__ xcH,
              const uint4* __restrict__ erec, const float* __restrict__ we_,
              const float* __restrict__ w2_, const float* __restrict__ b2p,
              uint2* __restrict__ catS, int E)
{
    const int lane = threadIdx.x & 63;
    const int q = lane & 3;
    const int gwid = (blockIdx.x * blockDim.x + threadIdx.x) >> 6;
    const int nw = (gridDim.x * blockDim.x) >> 6;

    float we[32], w2[32];
#pragma unroll
    for (int ch = 0; ch < 4; ++ch) {
        const float4 a0 = ((const float4*)we_)[ch * 8 + q * 2];
        const float4 a1 = ((const float4*)we_)[ch * 8 + q * 2 + 1];
        we[ch * 8 + 0] = a0.x; we[ch * 8 + 1] = a0.y; we[ch * 8 + 2] = a0.z; we[ch * 8 + 3] = a0.w;
        we[ch * 8 + 4] = a1.x; we[ch * 8 + 5] = a1.y; we[ch * 8 + 6] = a1.z; we[ch * 8 + 7] = a1.w;
        const float4 c0 = ((const float4*)w2_)[ch * 8 + q * 2];
        const float4 c1 = ((const float4*)w2_)[ch * 8 + q * 2 + 1];
        w2[ch * 8 + 0] = c0.x; w2[ch * 8 + 1] = c0.y; w2[ch * 8 + 2] = c0.z; w2[ch * 8 + 3] = c0.w;
        w2[ch * 8 + 4] = c1.x; w2[ch * 8 + 5] = c1.y; w2[ch * 8 + 6] = c1.z; w2[ch * 8 + 7] = c1.w;
    }
    const float b2 = *b2p;

    for (int base = gwid * 16; base < E; base += nw * 16) {
        const int e = base + (lane >> 2);
        const bool valid = e < E;
        const int ec = valid ? e : E - 1;
        const uint4 rec = erec[ec];
        const int r = (int)rec.x, c = (int)rec.y;
        const float eax = __uint_as_float(rec.z);
        const float emv = __uint_as_float(rec.w);
        const unsigned short* xr = xrH + (size_t)r * 128;
        const unsigned short* xc = xcH + (size_t)c * 128;
        float p = 0.f;
#pragma unroll
        for (int ch = 0; ch < 4; ++ch) {
            const uint4 pa = *(const uint4*)(xr + ch * 32 + q * 8);
            const uint4 pb = *(const uint4*)(xc + ch * 32 + q * 8);
            float xa[8], xb[8];
            bf8f(pa, xa); bf8f(pb, xb);
#pragma unroll
            for (int i = 0; i < 8; ++i) {
                const float t = xa[i] + xb[i] + eax * we[ch * 8 + i];
                p += t * sigf(t) * w2[ch * 8 + i];
            }
        }
        p = quad_add_all(p);
        const float att = sigf(p + b2) * emv;
        if (valid && q == 0) catS[e] = make_uint2(rec.y, __float_as_uint(att));
    }
}

// ---- row accumulation: msgH[r] = bf16( sum att * xm[col] ) ----
__global__ __launch_bounds__(256)
void accum_k(const unsigned short* __restrict__ xmH, const int* __restrict__ off,
             const uint2* __restrict__ catS, unsigned short* __restrict__ msgH, int N)
{
    const int lane = threadIdx.x & 63;
    const int g = lane >> 4, l = lane & 15;
    const int gwid = (blockIdx.x * blockDim.x + threadIdx.x) >> 6;
    const int nw = (gridDim.x * blockDim.x) >> 6;
    const uint4* xm4 = (const uint4*)xmH;

    for (int wid = gwid; wid < N; wid += nw) {
        int j0 = off[wid];
        const int jend = off[wid + 1];
        float acc[8] = {0.f, 0.f, 0.f, 0.f, 0.f, 0.f, 0.f, 0.f};

        // 16 edges in flight per iteration (4 per group)
        for (; j0 + 16 <= jend; j0 += 16) {
            uint2 ca[4]; uint4 pk[4];
#pragma unroll
            for (int u = 0; u < 4; ++u) ca[u] = catS[j0 + u * 4 + g];
#pragma unroll
            for (int u = 0; u < 4; ++u) pk[u] = xm4[(size_t)ca[u].x * 16 + l];
#pragma unroll
            for (int u = 0; u < 4; ++u) {
                const float att = __uint_as_float(ca[u].y);
                float xm[8];
                bf8f(pk[u], xm);
#pragma unroll
                for (int i = 0; i < 8; ++i) acc[i] = fmaf(att, xm[i], acc[i]);
            }
        }
        for (; j0 + 8 <= jend; j0 += 8) {
            const uint2 caA = catS[j0 + g];
            const uint2 caB = catS[j0 + 4 + g];
            const uint4 pA = xm4[(size_t)caA.x * 16 + l];
            const uint4 pB = xm4[(size_t)caB.x * 16 + l];
            const float attA = __uint_as_float(caA.y);
            const float attB = __uint_as_float(caB.y);
            float xmA[8], xmB[8];
            bf8f(pA, xmA); bf8f(pB, xmB);
#pragma unroll
            for (int i = 0; i < 8; ++i)
                acc[i] = fmaf(attB, xmB[i], fmaf(attA, xmA[i], acc[i]));
        }
        for (; j0 < jend; j0 += 4) {
            const int je = j0 + g;
            const bool valid = je < jend;
            const int jc = valid ? je : jend - 1;
            const uint2 ca = catS[jc];
            const uint4 p = xm4[(size_t)ca.x * 16 + l];
            const float att = valid ? __uint_as_float(ca.y) : 0.f;
            float xm[8];
            bf8f(p, xm);
#pragma unroll
            for (int i = 0; i < 8; ++i) acc[i] = fmaf(att, xm[i], acc[i]);
        }

#pragma unroll
        for (int i = 0; i < 8; ++i) {
            acc[i] += __shfl_xor(acc[i], 16);
            acc[i] += __shfl_xor(acc[i], 32);
        }
        if (g == 0) {
            uint4 pk;
            pk.x = f2bf2(acc[0], acc[1]); pk.y = f2bf2(acc[2], acc[3]);
            pk.z = f2bf2(acc[4], acc[5]); pk.w = f2bf2(acc[6], acc[7]);
            ((uint4*)msgH)[(size_t)wid * 16 + l] = pk;
        }
    }
}

extern "C" void kernel_launch(void* const* d_in, const int* in_sizes, int n_in,
                              void* d_out, int out_size, void* d_ws, size_t ws_size,
                              hipStream_t stream)
{
    const float* h        = (const float*)d_in[0];
    const float* edge_attr= (const float*)d_in[1];
    const int*   row      = (const int*)d_in[2];
    const int*   col      = (const int*)d_in[3];
    const float* edge_mask= (const float*)d_in[5];
    const float* lin_w    = (const float*)d_in[6];
    const float* lin_b    = (const float*)d_in[7];
    const float* msg_w1   = (const float*)d_in[8];
    const float* msg_b1   = (const float*)d_in[9];
    const float* msg_ln_g = (const float*)d_in[10];
    const float* msg_ln_b = (const float*)d_in[11];
    const float* msg_w2   = (const float*)d_in[12];
    const float* msg_b2   = (const float*)d_in[13];
    const float* att_w1   = (const float*)d_in[14];
    const float* att_b1   = (const float*)d_in[15];
    const float* att_w2   = (const float*)d_in[16];
    const float* att_b2   = (const float*)d_in[17];
    const float* out_w1   = (const float*)d_in[18];
    const float* out_b1   = (const float*)d_in[19];
    const float* out_ln_g = (const float*)d_in[20];
    const float* out_ln_b = (const float*)d_in[21];
    const float* out_w2   = (const float*)d_in[22];
    const float* out_b2   = (const float*)d_in[23];
    const float* ln_g     = (const float*)d_in[24];
    const float* ln_b     = (const float*)d_in[25];

    const int N = in_sizes[0] / 128;
    const int E = in_sizes[2];
    const size_t NF = (size_t)N * 128;

    unsigned short* xbH  = (unsigned short*)d_ws;       // bf16 [N][128] x
    unsigned short* xrH  = xbH + NF;                    // bf16 [N][128]
    unsigned short* xcH  = xrH + NF;                    // bf16 [N][128]
    unsigned short* xmH  = xcH + NF;                    // bf16 [N][128]
    unsigned short* msgH = xmH + NF;                    // bf16 [N][128]
    int*    cnt   = (int*)(msgH + NF);                  // N (reused as cursor)
    int*    off   = cnt + N;                            // N+1 (alloc N+8)
    int*    btot  = off + N + 8;                        // 64
    int*    bexc  = btot + 64;                          // 64 (+pad to 16B align)
    uint4*  erec  = (uint4*)(bexc + 64 + 24);           // E records (16B aligned)
    uint2*  catS  = (uint2*)(erec + E);                 // E
    unsigned short* wp = (unsigned short*)(catS + E);   // 8*16384 bf16
    float* bias256 = (float*)(wp + 8 * 16384);

    const int gb = (N + 63) / 64;
    const int nb = (N + 1023) / 1024;
    const int sgrid = (E + 256 * 4 - 1) / (256 * 4);    // ~4 edges/thread

    prep_w<<<513, 256, 0, stream>>>(lin_w, msg_w1, msg_w2, att_w1, out_w1, out_w2,
                                    att_b1, wp, bias256);
    hipMemsetAsync(cnt, 0, (size_t)N * sizeof(int), stream);
    hist_k<<<1024, 256, 0, stream>>>(row, cnt, E);
    scan_a<<<nb, 1024, 0, stream>>>(cnt, off, btot, N);
    scan_b<<<1, 64, 0, stream>>>(btot, bexc, off, N, nb, E);
    scan_c<<<nb, 1024, 0, stream>>>(off, bexc, cnt, N);
    scatter_k<<<sgrid, 256, 0, stream>>>(row, col, edge_attr, edge_mask,
                                         cnt, erec, E);

    // x = bf16(h @ lin_w + lin_b)
    gemm_mfma<8, 0, 0><<<gb, 256, 0, stream>>>(h, wp, lin_b, xbH, 128, nullptr, 0, N);
    // xr|xc = x @ att_w1[0:256] + [b1|0]           (split destinations)
    gemm_mfma<16, 1, 1><<<gb, 256, 0, stream>>>(xbH, wp + 3 * 16384, bias256, xrH, 128, xcH, 128, N);
    // att scalars for every edge (sorted order)
    att_edge<<<2048, 256, 0, stream>>>(xrH, xcH, erec,
                                       att_w1 + 256 * 128, att_w2, att_b2, catS, E);

    // xm = (LN(silu(x @ msg_w1 + msg_b1))) @ msg_w2 + msg_b2   (fused, bf16)
    gemm2_mfma<0><<<gb, 256, 0, stream>>>(xbH, wp + 16384, msg_b1, msg_ln_g, msg_ln_b,
                                          wp + 2 * 16384, msg_b2, nullptr, nullptr,
                                          nullptr, xmH, N);

    // msg[r] = sum att * xm[col]  (bf16 out)
    accum_k<<<2048, 256, 0, stream>>>(xmH, off, catS, msgH, N);

    // out = LN(x + (LN(silu(msg @ out_w1 + out_b1))) @ out_w2 + out_b2)  (fused, f32)
    gemm2_mfma<3><<<gb, 256, 0, stream>>>(msgH, wp + 5 * 16384, out_b1, out_ln_g, out_ln_b,
                                          wp + 6 * 16384, out_b2, ln_g, ln_b,
                                          xbH, (float*)d_out, N);
}

// Round 10
// 231.550 us; speedup vs baseline: 1.3753x; 1.0756x over previous
//
#include <hip/hip_runtime.h>

#define LN_EPS 1e-5f

typedef __attribute__((ext_vector_type(8))) short short8;
typedef __attribute__((ext_vector_type(4))) float f32x4;

// sigmoid via native exp + rcp (NO IEEE division -- v_div_* chain is ~10 VALU ops)
__device__ __forceinline__ float sigf(float x) {
    return __builtin_amdgcn_rcpf(1.0f + __expf(-x));
}

__device__ __forceinline__ unsigned short f2bf(float f) {
    unsigned u = __float_as_uint(f);
    return (unsigned short)((u + 0x7fffu + ((u >> 16) & 1u)) >> 16);
}
__device__ __forceinline__ unsigned f2bf2(float lo, float hi) {
    return (unsigned)f2bf(lo) | ((unsigned)f2bf(hi) << 16);
}
__device__ __forceinline__ void bf2f(unsigned u, float& lo, float& hi) {
    lo = __uint_as_float(u << 16);
    hi = __uint_as_float(u & 0xffff0000u);
}
__device__ __forceinline__ void bf8f(uint4 p, float* o) {
    bf2f(p.x, o[0], o[1]); bf2f(p.y, o[2], o[3]);
    bf2f(p.z, o[4], o[5]); bf2f(p.w, o[6], o[7]);
}
__device__ __forceinline__ float bf1f(unsigned short s) {
    return __uint_as_float(((unsigned)s) << 16);
}

// butterfly sum over each quad (lanes 4k..4k+3) via DPP quad_perm — no DS ops
__device__ __forceinline__ float quad_add_all(float x) {
    int v = __builtin_amdgcn_update_dpp(0, __float_as_int(x), 0xB1, 0xF, 0xF, true); // [1,0,3,2]
    x += __int_as_float(v);
    v = __builtin_amdgcn_update_dpp(0, __float_as_int(x), 0x4E, 0xF, 0xF, true);     // [2,3,0,1]
    x += __int_as_float(v);
    return x;
}

// ---- weight prep: f32 [128][128] row-major -> fragment-linear bf16 ----
__global__ __launch_bounds__(256)
void prep_w(const float* __restrict__ lin_w, const float* __restrict__ msg_w1,
            const float* __restrict__ msg_w2, const float* __restrict__ att_w1,
            const float* __restrict__ out_w1, const float* __restrict__ out_w2,
            const float* __restrict__ att_b1, unsigned short* __restrict__ wp,
            float* __restrict__ bias256)
{
    const int idx = blockIdx.x * 256 + threadIdx.x;
    if (idx < 8 * 16384) {
        const int m = idx >> 14, r = idx & 16383;
        const int k = r >> 7, n = r & 127;
        const float* src; int slot; int fnBase = 0;
        switch (m) {
            case 0: src = lin_w;  slot = 0; break;
            case 1: src = msg_w1; slot = 1; break;
            case 2: src = msg_w2; slot = 2; break;
            case 3: src = att_w1; slot = 3; break;
            case 4: src = att_w1 + 128 * 128; slot = 3; fnBase = 8; break;
            case 5: src = out_w1; slot = 5; break;
            default: src = out_w2; slot = 6; break;
        }
        const float v = src[k * 128 + n];
        const int fn = fnBase + (n >> 4);
        const int fk = k >> 5, kb = (k >> 3) & 3, j = k & 7;
        const size_t dst = (size_t)slot * 16384 + ((size_t)((fn * 4 + fk) * 64 + (n & 15) + 16 * kb)) * 8 + j;
        wp[dst] = f2bf(v);
    } else if (idx < 8 * 16384 + 256) {
        const int t = idx - 8 * 16384;
        bias256[t] = (t < 128) ? att_b1[t] : 0.f;
    }
}

// ---- A-fragment loaders (direct from row-major global, no LDS) ----
__device__ __forceinline__ short8 ldA_bf(const unsigned short* A, size_t row, int k0) {
    return *(const short8*)(A + row * 128 + k0);
}
__device__ __forceinline__ short8 ldA_f32(const float* A, size_t row, int k0) {
    const float* ap = A + row * 128 + k0;
    const float4 f0 = *(const float4*)ap;
    const float4 f1 = *(const float4*)(ap + 4);
    union { unsigned u[4]; short8 s; } v;
    v.u[0] = f2bf2(f0.x, f0.y); v.u[1] = f2bf2(f0.z, f0.w);
    v.u[2] = f2bf2(f1.x, f1.y); v.u[3] = f2bf2(f1.z, f1.w);
    return v.s;
}

// ---- barrier-free bf16 MFMA GEMM: bf16_out(A[N,128] @ W + bias) ----
// ABF: A bf16.  SPLIT (NFN=16): fn<8 -> C1, fn>=8 -> C2 (fn rebased).
template<int NFN, int ABF, int SPLIT>
__global__ __launch_bounds__(256, NFN == 8 ? 4 : 3)
void gemm_mfma(const void* __restrict__ Av, const unsigned short* __restrict__ Wp,
               const float* __restrict__ bias,
               unsigned short* __restrict__ C1, int ld1,
               unsigned short* __restrict__ C2, int ld2, int nrows)
{
    const int tid = threadIdx.x;
    const int w = tid >> 6, lane = tid & 63;
    const int r0 = blockIdx.x * 64;
    const int arow = r0 + w * 16 + (lane & 15);
    const size_t rowc = (arow < nrows) ? (size_t)arow : (size_t)(nrows - 1);
    const int kh = (lane >> 4) * 8;

    short8 a[4];
#pragma unroll
    for (int fk = 0; fk < 4; ++fk)
        a[fk] = ABF ? ldA_bf((const unsigned short*)Av, rowc, fk * 32 + kh)
                    : ldA_f32((const float*)Av, rowc, fk * 32 + kh);

    const short8* Bf = (const short8*)Wp;
    f32x4 acc[NFN];
#pragma unroll
    for (int fn = 0; fn < NFN; ++fn) acc[fn] = (f32x4){0.f, 0.f, 0.f, 0.f};
#pragma unroll
    for (int fk = 0; fk < 4; ++fk)
#pragma unroll
        for (int fn = 0; fn < NFN; ++fn)
            acc[fn] = __builtin_amdgcn_mfma_f32_16x16x32_bf16(a[fk], Bf[(fn * 4 + fk) * 64 + lane], acc[fn], 0, 0, 0);

    const int cn = lane & 15, rq = lane >> 4;
    float bv[NFN];
#pragma unroll
    for (int fn = 0; fn < NFN; ++fn) bv[fn] = bias ? bias[fn * 16 + cn] : 0.f;

#pragma unroll
    for (int reg = 0; reg < 4; ++reg) {
        const int gr = r0 + w * 16 + rq * 4 + reg;
        if (gr < nrows) {
#pragma unroll
            for (int fn = 0; fn < NFN; ++fn) {
                const float v = acc[fn][reg] + bv[fn];
                if (SPLIT) {
                    if (fn < 8) C1[(size_t)gr * ld1 + fn * 16 + cn] = f2bf(v);
                    else        C2[(size_t)gr * ld2 + (fn - 8) * 16 + cn] = f2bf(v);
                } else {
                    C1[(size_t)gr * ld1 + fn * 16 + cn] = f2bf(v);
                }
            }
        }
    }
}

// ---- fused double GEMM: C = epi2( LN(silu(A@W1+b1)) @ W2 + b2 ) ----
// A bf16. Stage-1 handoff per-wave via XOR-swizzled LDS (no barrier).
// EPI2 0: +b2, bf16 C.  EPI2 3: +b2+res(bf16) then LN(ln2), f32 C.
template<int EPI2>
__global__ __launch_bounds__(256, 4)
void gemm2_mfma(const unsigned short* __restrict__ Av,
                const unsigned short* __restrict__ Wp1, const float* __restrict__ b1,
                const float* __restrict__ ln1g, const float* __restrict__ ln1b,
                const unsigned short* __restrict__ Wp2, const float* __restrict__ b2,
                const float* __restrict__ ln2g, const float* __restrict__ ln2b,
                const unsigned short* __restrict__ resH, void* __restrict__ Cv, int nrows)
{
    __shared__ unsigned short hof[4 * 2048];   // 16 KiB, 4 KiB per wave
    const int tid = threadIdx.x;
    const int w = tid >> 6, lane = tid & 63;
    const int r0 = blockIdx.x * 64;
    const int arow = r0 + w * 16 + (lane & 15);
    const size_t rowc = (arow < nrows) ? (size_t)arow : (size_t)(nrows - 1);
    const int kh = (lane >> 4) * 8;
    const int cn = lane & 15, rq = lane >> 4;

    short8 a[4];
#pragma unroll
    for (int fk = 0; fk < 4; ++fk)
        a[fk] = ldA_bf(Av, rowc, fk * 32 + kh);

    const short8* B1f = (const short8*)Wp1;
    f32x4 acc[8];
#pragma unroll
    for (int fn = 0; fn < 8; ++fn) acc[fn] = (f32x4){0.f, 0.f, 0.f, 0.f};
#pragma unroll
    for (int fk = 0; fk < 4; ++fk)
#pragma unroll
        for (int fn = 0; fn < 8; ++fn)
            acc[fn] = __builtin_amdgcn_mfma_f32_16x16x32_bf16(a[fk], B1f[(fn * 4 + fk) * 64 + lane], acc[fn], 0, 0, 0);

    // epilogue-1: silu + LN -> wave-private swizzled LDS handoff
    unsigned short* hw = hof + w * 2048;
    {
        float bv[8], gv[8], bbv[8];
#pragma unroll
        for (int fn = 0; fn < 8; ++fn) {
            bv[fn] = b1[fn * 16 + cn]; gv[fn] = ln1g[fn * 16 + cn]; bbv[fn] = ln1b[fn * 16 + cn];
        }
#pragma unroll
        for (int reg = 0; reg < 4; ++reg) {
            float val[8];
            float sum = 0.f, sq = 0.f;
#pragma unroll
            for (int fn = 0; fn < 8; ++fn) {
                float v = acc[fn][reg] + bv[fn];
                v = v * sigf(v);
                val[fn] = v; sum += v; sq += v * v;
            }
#pragma unroll
            for (int m = 1; m < 16; m <<= 1) { sum += __shfl_xor(sum, m); sq += __shfl_xor(sq, m); }
            const float mean = sum * (1.f / 128.f);
            const float var = sq * (1.f / 128.f) - mean * mean;
            const float rstd = rsqrtf(var + LN_EPS);
            const int row16 = rq * 4 + reg;
            const int sw = (row16 & 7) << 3;           // XOR swizzle (ushort units)
#pragma unroll
            for (int fn = 0; fn < 8; ++fn) {
                const float o = (val[fn] - mean) * rstd * gv[fn] + bbv[fn];
                hw[row16 * 128 + ((fn * 16 + cn) ^ sw)] = f2bf(o);
            }
        }
    }

    // stage-2 A frags from handoff (intra-wave lgkmcnt ordering only)
    short8 a2[4];
    {
        const int row16 = lane & 15;
        const int sw = (row16 & 7) << 3;
#pragma unroll
        for (int fk = 0; fk < 4; ++fk)
            a2[fk] = *(const short8*)(hw + row16 * 128 + ((fk * 32 + kh) ^ sw));
    }

    const short8* B2f = (const short8*)Wp2;
    f32x4 acc2[8];
#pragma unroll
    for (int fn = 0; fn < 8; ++fn) acc2[fn] = (f32x4){0.f, 0.f, 0.f, 0.f};
#pragma unroll
    for (int fk = 0; fk < 4; ++fk)
#pragma unroll
        for (int fn = 0; fn < 8; ++fn)
            acc2[fn] = __builtin_amdgcn_mfma_f32_16x16x32_bf16(a2[fk], B2f[(fn * 4 + fk) * 64 + lane], acc2[fn], 0, 0, 0);

    // epilogue-2
    float bv2[8];
#pragma unroll
    for (int fn = 0; fn < 8; ++fn) bv2[fn] = b2[fn * 16 + cn];

    if (EPI2 == 0) {
        unsigned short* Ch = (unsigned short*)Cv;
#pragma unroll
        for (int reg = 0; reg < 4; ++reg) {
            const int gr = r0 + w * 16 + rq * 4 + reg;
            if (gr < nrows) {
#pragma unroll
                for (int fn = 0; fn < 8; ++fn)
                    Ch[(size_t)gr * 128 + fn * 16 + cn] = f2bf(acc2[fn][reg] + bv2[fn]);
            }
        }
    } else {
        float* Cf = (float*)Cv;
        float gv[8], bbv[8];
#pragma unroll
        for (int fn = 0; fn < 8; ++fn) { gv[fn] = ln2g[fn * 16 + cn]; bbv[fn] = ln2b[fn * 16 + cn]; }
#pragma unroll
        for (int reg = 0; reg < 4; ++reg) {
            const int gr = r0 + w * 16 + rq * 4 + reg;
            const int grc = gr < nrows ? gr : nrows - 1;
            float val[8];
            float sum = 0.f, sq = 0.f;
#pragma unroll
            for (int fn = 0; fn < 8; ++fn) {
                float v = acc2[fn][reg] + bv2[fn] + bf1f(resH[(size_t)grc * 128 + fn * 16 + cn]);
                val[fn] = v; sum += v; sq += v * v;
            }
#pragma unroll
            for (int m = 1; m < 16; m <<= 1) { sum += __shfl_xor(sum, m); sq += __shfl_xor(sq, m); }
            const float mean = sum * (1.f / 128.f);
            const float var = sq * (1.f / 128.f) - mean * mean;
            const float rstd = rsqrtf(var + LN_EPS);
            if (gr < nrows) {
#pragma unroll
                for (int fn = 0; fn < 8; ++fn)
                    Cf[(size_t)gr * 128 + fn * 16 + cn] = (val[fn] - mean) * rstd * gv[fn] + bbv[fn];
            }
        }
    }
}

// ---- histogram + per-edge rank in ONE atomic pass (4-deep ILP) ----
__global__ __launch_bounds__(256)
void hist_rank(const int* __restrict__ row, int* __restrict__ cnt,
               int* __restrict__ rank, int E)
{
    const int tid = blockIdx.x * blockDim.x + threadIdx.x;
    const int stride = gridDim.x * blockDim.x;
    for (int e0 = tid; e0 < E; e0 += stride * 4) {
        int r[4]; bool val[4];
#pragma unroll
        for (int u = 0; u < 4; ++u) {
            const int e = e0 + u * stride;
            val[u] = e < E;
            r[u] = val[u] ? row[e] : 0;
        }
        int rk[4];
#pragma unroll
        for (int u = 0; u < 4; ++u)
            if (val[u]) rk[u] = atomicAdd(&cnt[r[u]], 1);
#pragma unroll
        for (int u = 0; u < 4; ++u)
            if (val[u]) rank[e0 + u * stride] = rk[u];
    }
}

__global__ __launch_bounds__(1024)
void scan_a(const int* __restrict__ cnt, int* __restrict__ off,
            int* __restrict__ btot, int n)
{
    __shared__ int wsum[16];
    const int tid = threadIdx.x, lane = tid & 63, wv = tid >> 6;
    const int i = blockIdx.x * 1024 + tid;
    const int v = (i < n) ? cnt[i] : 0;
    int incl = v;
#pragma unroll
    for (int d = 1; d < 64; d <<= 1) { int t = __shfl_up(incl, d); if (lane >= d) incl += t; }
    if (lane == 63) wsum[wv] = incl;
    __syncthreads();
    if (tid == 0) {
        int run = 0;
        for (int ww = 0; ww < 16; ++ww) { int t = wsum[ww]; wsum[ww] = run; run += t; }
    }
    __syncthreads();
    if (i < n) off[i] = wsum[wv] + incl - v;
    if (tid == 1023) btot[blockIdx.x] = wsum[15] + incl;
}

__global__ __launch_bounds__(64)
void scan_b(int* __restrict__ btot, int* __restrict__ bexc,
            int* __restrict__ off, int n, int nb, int E)
{
    const int t = threadIdx.x;
    const int v = (t < nb) ? btot[t] : 0;
    int incl = v;
#pragma unroll
    for (int d = 1; d < 64; d <<= 1) { int u = __shfl_up(incl, d); if (t >= d) incl += u; }
    if (t < nb) bexc[t] = incl - v;
    if (t == 0) off[n] = E;
}

__global__ __launch_bounds__(1024)
void scan_c(int* __restrict__ off, const int* __restrict__ bexc, int n)
{
    const int i = blockIdx.x * 1024 + threadIdx.x;
    if (i < n) off[i] += bexc[blockIdx.x];
}

// ---- edge-parallel attention, quad-per-edge, ORIGINAL edge order ----
// fused scatter: catS[off[row]+rank] = (col, att)  -- 8B random store
__global__ __launch_bounds__(256, 4)
void att_edge(const unsigned short* __restrict__ xrH,
              const unsigned short* __restrict__ xcH,
              const int* __restrict__ row, const int* __restrict__ col,
              const float* __restrict__ ea, const float* __restrict__ em,
              const int* __restrict__ rank, const int* __restrict__ off,
              const float* __restrict__ we_, const float* __restrict__ w2_,
              const float* __restrict__ b2p, uint2* __restrict__ catS, int E)
{
    const int lane = threadIdx.x & 63;
    const int q = lane & 3;
    const int gwid = (blockIdx.x * blockDim.x + threadIdx.x) >> 6;
    const int nw = (gridDim.x * blockDim.x) >> 6;

    float we[32], w2[32];
#pragma unroll
    for (int ch = 0; ch < 4; ++ch) {
        const float4 a0 = ((const float4*)we_)[ch * 8 + q * 2];
        const float4 a1 = ((const float4*)we_)[ch * 8 + q * 2 + 1];
        we[ch * 8 + 0] = a0.x; we[ch * 8 + 1] = a0.y; we[ch * 8 + 2] = a0.z; we[ch * 8 + 3] = a0.w;
        we[ch * 8 + 4] = a1.x; we[ch * 8 + 5] = a1.y; we[ch * 8 + 6] = a1.z; we[ch * 8 + 7] = a1.w;
        const float4 c0 = ((const float4*)w2_)[ch * 8 + q * 2];
        const float4 c1 = ((const float4*)w2_)[ch * 8 + q * 2 + 1];
        w2[ch * 8 + 0] = c0.x; w2[ch * 8 + 1] = c0.y; w2[ch * 8 + 2] = c0.z; w2[ch * 8 + 3] = c0.w;
        w2[ch * 8 + 4] = c1.x; w2[ch * 8 + 5] = c1.y; w2[ch * 8 + 6] = c1.z; w2[ch * 8 + 7] = c1.w;
    }
    const float b2 = *b2p;

    for (int base = gwid * 16; base < E; base += nw * 16) {
        const int e = base + (lane >> 2);
        const bool valid = e < E;
        const int ec = valid ? e : E - 1;
        const int r = row[ec], c = col[ec];
        const float eax = ea[ec], emv = em[ec];
        const unsigned short* xr = xrH + (size_t)r * 128;
        const unsigned short* xc = xcH + (size_t)c * 128;
        float p = 0.f;
#pragma unroll
        for (int ch = 0; ch < 4; ++ch) {
            const uint4 pa = *(const uint4*)(xr + ch * 32 + q * 8);
            const uint4 pb = *(const uint4*)(xc + ch * 32 + q * 8);
            float xa[8], xb[8];
            bf8f(pa, xa); bf8f(pb, xb);
#pragma unroll
            for (int i = 0; i < 8; ++i) {
                const float t = xa[i] + xb[i] + eax * we[ch * 8 + i];
                p += t * sigf(t) * w2[ch * 8 + i];
            }
        }
        p = quad_add_all(p);
        const float att = sigf(p + b2) * emv;
        if (valid && q == 0) {
            const int pos = off[r] + rank[ec];
            catS[pos] = make_uint2((unsigned)c, __float_as_uint(att));
        }
    }
}

// ---- row accumulation: msgH[r] = bf16( sum att * xm[col] ) ----
__global__ __launch_bounds__(256)
void accum_k(const unsigned short* __restrict__ xmH, const int* __restrict__ off,
             const uint2* __restrict__ catS, unsigned short* __restrict__ msgH, int N)
{
    const int lane = threadIdx.x & 63;
    const int g = lane >> 4, l = lane & 15;
    const int gwid = (blockIdx.x * blockDim.x + threadIdx.x) >> 6;
    const int nw = (gridDim.x * blockDim.x) >> 6;
    const uint4* xm4 = (const uint4*)xmH;

    for (int wid = gwid; wid < N; wid += nw) {
        int j0 = off[wid];
        const int jend = off[wid + 1];
        float acc[8] = {0.f, 0.f, 0.f, 0.f, 0.f, 0.f, 0.f, 0.f};

        // 16 edges in flight per iteration (4 per group)
        for (; j0 + 16 <= jend; j0 += 16) {
            uint2 ca[4]; uint4 pk[4];
#pragma unroll
            for (int u = 0; u < 4; ++u) ca[u] = catS[j0 + u * 4 + g];
#pragma unroll
            for (int u = 0; u < 4; ++u) pk[u] = xm4[(size_t)ca[u].x * 16 + l];
#pragma unroll
            for (int u = 0; u < 4; ++u) {
                const float att = __uint_as_float(ca[u].y);
                float xm[8];
                bf8f(pk[u], xm);
#pragma unroll
                for (int i = 0; i < 8; ++i) acc[i] = fmaf(att, xm[i], acc[i]);
            }
        }
        for (; j0 + 8 <= jend; j0 += 8) {
            const uint2 caA = catS[j0 + g];
            const uint2 caB = catS[j0 + 4 + g];
            const uint4 pA = xm4[(size_t)caA.x * 16 + l];
            const uint4 pB = xm4[(size_t)caB.x * 16 + l];
            const float attA = __uint_as_float(caA.y);
            const float attB = __uint_as_float(caB.y);
            float xmA[8], xmB[8];
            bf8f(pA, xmA); bf8f(pB, xmB);
#pragma unroll
            for (int i = 0; i < 8; ++i)
                acc[i] = fmaf(attB, xmB[i], fmaf(attA, xmA[i], acc[i]));
        }
        for (; j0 < jend; j0 += 4) {
            const int je = j0 + g;
            const bool valid = je < jend;
            const int jc = valid ? je : jend - 1;
            const uint2 ca = catS[jc];
            const uint4 p = xm4[(size_t)ca.x * 16 + l];
            const float att = valid ? __uint_as_float(ca.y) : 0.f;
            float xm[8];
            bf8f(p, xm);
#pragma unroll
            for (int i = 0; i < 8; ++i) acc[i] = fmaf(att, xm[i], acc[i]);
        }

#pragma unroll
        for (int i = 0; i < 8; ++i) {
            acc[i] += __shfl_xor(acc[i], 16);
            acc[i] += __shfl_xor(acc[i], 32);
        }
        if (g == 0) {
            uint4 pk;
            pk.x = f2bf2(acc[0], acc[1]); pk.y = f2bf2(acc[2], acc[3]);
            pk.z = f2bf2(acc[4], acc[5]); pk.w = f2bf2(acc[6], acc[7]);
            ((uint4*)msgH)[(size_t)wid * 16 + l] = pk;
        }
    }
}

extern "C" void kernel_launch(void* const* d_in, const int* in_sizes, int n_in,
                              void* d_out, int out_size, void* d_ws, size_t ws_size,
                              hipStream_t stream)
{
    const float* h        = (const float*)d_in[0];
    const float* edge_attr= (const float*)d_in[1];
    const int*   row      = (const int*)d_in[2];
    const int*   col      = (const int*)d_in[3];
    const float* edge_mask= (const float*)d_in[5];
    const float* lin_w    = (const float*)d_in[6];
    const float* lin_b    = (const float*)d_in[7];
    const float* msg_w1   = (const float*)d_in[8];
    const float* msg_b1   = (const float*)d_in[9];
    const float* msg_ln_g = (const float*)d_in[10];
    const float* msg_ln_b = (const float*)d_in[11];
    const float* msg_w2   = (const float*)d_in[12];
    const float* msg_b2   = (const float*)d_in[13];
    const float* att_w1   = (const float*)d_in[14];
    const float* att_b1   = (const float*)d_in[15];
    const float* att_w2   = (const float*)d_in[16];
    const float* att_b2   = (const float*)d_in[17];
    const float* out_w1   = (const float*)d_in[18];
    const float* out_b1   = (const float*)d_in[19];
    const float* out_ln_g = (const float*)d_in[20];
    const float* out_ln_b = (const float*)d_in[21];
    const float* out_w2   = (const float*)d_in[22];
    const float* out_b2   = (const float*)d_in[23];
    const float* ln_g     = (const float*)d_in[24];
    const float* ln_b     = (const float*)d_in[25];

    const int N = in_sizes[0] / 128;
    const int E = in_sizes[2];
    const size_t NF = (size_t)N * 128;

    unsigned short* xbH  = (unsigned short*)d_ws;       // bf16 [N][128] x
    unsigned short* xrH  = xbH + NF;                    // bf16 [N][128]
    unsigned short* xcH  = xrH + NF;                    // bf16 [N][128]
    unsigned short* xmH  = xcH + NF;                    // bf16 [N][128]
    unsigned short* msgH = xmH + NF;                    // bf16 [N][128]
    int*    cnt   = (int*)(msgH + NF);                  // N
    int*    off   = cnt + N;                            // N+1 (alloc N+8)
    int*    btot  = off + N + 8;                        // 64
    int*    bexc  = btot + 64;                          // 64
    int*    rank  = bexc + 64;                          // E
    uint2*  catS  = (uint2*)(rank + E);                 // E (8B-aligned: even #ints before)
    unsigned short* wp = (unsigned short*)(catS + E);   // 8*16384 bf16
    float* bias256 = (float*)(wp + 8 * 16384);

    const int gb = (N + 63) / 64;
    const int nb = (N + 1023) / 1024;
    const int hgrid = (E + 256 * 4 - 1) / (256 * 4);    // ~4 edges/thread

    prep_w<<<513, 256, 0, stream>>>(lin_w, msg_w1, msg_w2, att_w1, out_w1, out_w2,
                                    att_b1, wp, bias256);
    hipMemsetAsync(cnt, 0, (size_t)N * sizeof(int), stream);
    // ONE atomic pass: histogram + per-edge rank
    hist_rank<<<hgrid, 256, 0, stream>>>(row, cnt, rank, E);
    scan_a<<<nb, 1024, 0, stream>>>(cnt, off, btot, N);
    scan_b<<<1, 64, 0, stream>>>(btot, bexc, off, N, nb, E);
    scan_c<<<nb, 1024, 0, stream>>>(off, bexc, N);

    // x = bf16(h @ lin_w + lin_b)
    gemm_mfma<8, 0, 0><<<gb, 256, 0, stream>>>(h, wp, lin_b, xbH, 128, nullptr, 0, N);
    // xr|xc = x @ att_w1[0:256] + [b1|0]           (split destinations)
    gemm_mfma<16, 1, 1><<<gb, 256, 0, stream>>>(xbH, wp + 3 * 16384, bias256, xrH, 128, xcH, 128, N);
    // att scalars, original edge order, fused scatter into sorted catS
    att_edge<<<2048, 256, 0, stream>>>(xrH, xcH, row, col, edge_attr, edge_mask,
                                       rank, off, att_w1 + 256 * 128, att_w2, att_b2,
                                       catS, E);

    // xm = (LN(silu(x @ msg_w1 + msg_b1))) @ msg_w2 + msg_b2   (fused, bf16)
    gemm2_mfma<0><<<gb, 256, 0, stream>>>(xbH, wp + 16384, msg_b1, msg_ln_g, msg_ln_b,
                                          wp + 2 * 16384, msg_b2, nullptr, nullptr,
                                          nullptr, xmH, N);

    // msg[r] = sum att * xm[col]  (bf16 out)
    accum_k<<<2048, 256, 0, stream>>>(xmH, off, catS, msgH, N);

    // out = LN(x + (LN(silu(msg @ out_w1 + out_b1))) @ out_w2 + out_b2)  (fused, f32)
    gemm2_mfma<3><<<gb, 256, 0, stream>>>(msgH, wp + 5 * 16384, out_b1, out_ln_g, out_ln_b,
                                          wp + 6 * 16384, out_b2, ln_g, ln_b,
                                          xbH, (float*)d_out, N);
}

// Round 11
// 230.912 us; speedup vs baseline: 1.3791x; 1.0028x over previous
//
#include <hip/hip_runtime.h>

#define LN_EPS 1e-5f

typedef __attribute__((ext_vector_type(8))) short short8;
typedef __attribute__((ext_vector_type(4))) float f32x4;

// sigmoid via native exp + rcp (NO IEEE division)
__device__ __forceinline__ float sigf(float x) {
    return __builtin_amdgcn_rcpf(1.0f + __expf(-x));
}

__device__ __forceinline__ unsigned short f2bf(float f) {
    unsigned u = __float_as_uint(f);
    return (unsigned short)((u + 0x7fffu + ((u >> 16) & 1u)) >> 16);
}
__device__ __forceinline__ unsigned f2bf2(float lo, float hi) {
    return (unsigned)f2bf(lo) | ((unsigned)f2bf(hi) << 16);
}
__device__ __forceinline__ void bf2f(unsigned u, float& lo, float& hi) {
    lo = __uint_as_float(u << 16);
    hi = __uint_as_float(u & 0xffff0000u);
}
__device__ __forceinline__ void bf8f(uint4 p, float* o) {
    bf2f(p.x, o[0], o[1]); bf2f(p.y, o[2], o[3]);
    bf2f(p.z, o[4], o[5]); bf2f(p.w, o[6], o[7]);
}
__device__ __forceinline__ float bf1f(unsigned short s) {
    return __uint_as_float(((unsigned)s) << 16);
}

// butterfly sum over each quad via DPP quad_perm — no DS ops
__device__ __forceinline__ float quad_add_all(float x) {
    int v = __builtin_amdgcn_update_dpp(0, __float_as_int(x), 0xB1, 0xF, 0xF, true);
    x += __int_as_float(v);
    v = __builtin_amdgcn_update_dpp(0, __float_as_int(x), 0x4E, 0xF, 0xF, true);
    x += __int_as_float(v);
    return x;
}

// ---- weight prep: f32 [128][128] row-major -> fragment-linear bf16 ----
__global__ __launch_bounds__(256)
void prep_w(const float* __restrict__ lin_w, const float* __restrict__ msg_w1,
            const float* __restrict__ msg_w2, const float* __restrict__ att_w1,
            const float* __restrict__ out_w1, const float* __restrict__ out_w2,
            const float* __restrict__ att_b1, unsigned short* __restrict__ wp,
            float* __restrict__ bias256)
{
    const int idx = blockIdx.x * 256 + threadIdx.x;
    if (idx < 8 * 16384) {
        const int m = idx >> 14, r = idx & 16383;
        const int k = r >> 7, n = r & 127;
        const float* src; int slot; int fnBase = 0;
        switch (m) {
            case 0: src = lin_w;  slot = 0; break;
            case 1: src = msg_w1; slot = 1; break;
            case 2: src = msg_w2; slot = 2; break;
            case 3: src = att_w1; slot = 3; break;
            case 4: src = att_w1 + 128 * 128; slot = 3; fnBase = 8; break;
            case 5: src = out_w1; slot = 5; break;
            default: src = out_w2; slot = 6; break;
        }
        const float v = src[k * 128 + n];
        const int fn = fnBase + (n >> 4);
        const int fk = k >> 5, kb = (k >> 3) & 3, j = k & 7;
        const size_t dst = (size_t)slot * 16384 + ((size_t)((fn * 4 + fk) * 64 + (n & 15) + 16 * kb)) * 8 + j;
        wp[dst] = f2bf(v);
    } else if (idx < 8 * 16384 + 256) {
        const int t = idx - 8 * 16384;
        bias256[t] = (t < 128) ? att_b1[t] : 0.f;
    }
}

__device__ __forceinline__ short8 ldA_f32(const float* A, size_t row, int k0) {
    const float* ap = A + row * 128 + k0;
    const float4 f0 = *(const float4*)ap;
    const float4 f1 = *(const float4*)(ap + 4);
    union { unsigned u[4]; short8 s; } v;
    v.u[0] = f2bf2(f0.x, f0.y); v.u[1] = f2bf2(f0.z, f0.w);
    v.u[2] = f2bf2(f1.x, f1.y); v.u[3] = f2bf2(f1.z, f1.w);
    return v.s;
}
__device__ __forceinline__ short8 ldA_bf(const unsigned short* A, size_t row, int k0) {
    return *(const short8*)(A + row * 128 + k0);
}

// ---- fused FRONT kernel: lin -> {att-proj, msg1 -> msg2}, one dispatch ----
// Per-wave swizzled-LDS handoffs (no barriers). Writes xbH, xrH, xcH, xmH.
__global__ __launch_bounds__(256, 4)
void front_mfma(const float* __restrict__ h,
                const unsigned short* __restrict__ WpLin, const float* __restrict__ lin_b,
                const unsigned short* __restrict__ WpAtt, const float* __restrict__ bias256,
                const unsigned short* __restrict__ WpM1, const float* __restrict__ msg_b1,
                const float* __restrict__ m1g, const float* __restrict__ m1b,
                const unsigned short* __restrict__ WpM2, const float* __restrict__ msg_b2,
                unsigned short* __restrict__ xbH, unsigned short* __restrict__ xrH,
                unsigned short* __restrict__ xcH, unsigned short* __restrict__ xmH,
                int nrows)
{
    __shared__ unsigned short hofA[4 * 2048];
    __shared__ unsigned short hofB[4 * 2048];
    const int tid = threadIdx.x;
    const int w = tid >> 6, lane = tid & 63;
    const int r0 = blockIdx.x * 64;
    const int arow = r0 + w * 16 + (lane & 15);
    const size_t rowc = (arow < nrows) ? (size_t)arow : (size_t)(nrows - 1);
    const int kh = (lane >> 4) * 8;
    const int cn = lane & 15, rq = lane >> 4;
    unsigned short* hwA = hofA + w * 2048;
    unsigned short* hwB = hofB + w * 2048;

    // ---- stage 0: x = h @ lin_w + lin_b ----
    short8 a[4];
#pragma unroll
    for (int fk = 0; fk < 4; ++fk) a[fk] = ldA_f32(h, rowc, fk * 32 + kh);

    {
        const short8* Bf = (const short8*)WpLin;
        f32x4 accx[8];
#pragma unroll
        for (int fn = 0; fn < 8; ++fn) accx[fn] = (f32x4){0.f, 0.f, 0.f, 0.f};
#pragma unroll
        for (int fk = 0; fk < 4; ++fk)
#pragma unroll
            for (int fn = 0; fn < 8; ++fn)
                accx[fn] = __builtin_amdgcn_mfma_f32_16x16x32_bf16(a[fk], Bf[(fn * 4 + fk) * 64 + lane], accx[fn], 0, 0, 0);

        float bv[8];
#pragma unroll
        for (int fn = 0; fn < 8; ++fn) bv[fn] = lin_b[fn * 16 + cn];
#pragma unroll
        for (int reg = 0; reg < 4; ++reg) {
            const int gr = r0 + w * 16 + rq * 4 + reg;
            const int row16 = rq * 4 + reg;
            const int sw = (row16 & 7) << 3;
#pragma unroll
            for (int fn = 0; fn < 8; ++fn) {
                const unsigned short hb = f2bf(accx[fn][reg] + bv[fn]);
                if (gr < nrows) xbH[(size_t)gr * 128 + fn * 16 + cn] = hb;
                hwA[row16 * 128 + ((fn * 16 + cn) ^ sw)] = hb;
            }
        }
    }

    // x as A-frags (from handoff A)
    short8 ax[4];
    {
        const int row16 = lane & 15;
        const int sw = (row16 & 7) << 3;
#pragma unroll
        for (int fk = 0; fk < 4; ++fk)
            ax[fk] = *(const short8*)(hwA + row16 * 128 + ((fk * 32 + kh) ^ sw));
    }

    // ---- stage 1: xr|xc = x @ att_w1[0:256] + [b1|0] ----
    {
        const short8* Bf = (const short8*)WpAtt;
        f32x4 acca[16];
#pragma unroll
        for (int fn = 0; fn < 16; ++fn) acca[fn] = (f32x4){0.f, 0.f, 0.f, 0.f};
#pragma unroll
        for (int fk = 0; fk < 4; ++fk)
#pragma unroll
            for (int fn = 0; fn < 16; ++fn)
                acca[fn] = __builtin_amdgcn_mfma_f32_16x16x32_bf16(ax[fk], Bf[(fn * 4 + fk) * 64 + lane], acca[fn], 0, 0, 0);

        float bv[16];
#pragma unroll
        for (int fn = 0; fn < 16; ++fn) bv[fn] = bias256[fn * 16 + cn];
#pragma unroll
        for (int reg = 0; reg < 4; ++reg) {
            const int gr = r0 + w * 16 + rq * 4 + reg;
            if (gr < nrows) {
#pragma unroll
                for (int fn = 0; fn < 16; ++fn) {
                    const float v = acca[fn][reg] + bv[fn];
                    if (fn < 8) xrH[(size_t)gr * 128 + fn * 16 + cn] = f2bf(v);
                    else        xcH[(size_t)gr * 128 + (fn - 8) * 16 + cn] = f2bf(v);
                }
            }
        }
    }

    // ---- stage 2: m1 = LN(silu(x @ msg_w1 + msg_b1)) -> handoff B ----
    {
        const short8* Bf = (const short8*)WpM1;
        f32x4 acc1[8];
#pragma unroll
        for (int fn = 0; fn < 8; ++fn) acc1[fn] = (f32x4){0.f, 0.f, 0.f, 0.f};
#pragma unroll
        for (int fk = 0; fk < 4; ++fk)
#pragma unroll
            for (int fn = 0; fn < 8; ++fn)
                acc1[fn] = __builtin_amdgcn_mfma_f32_16x16x32_bf16(ax[fk], Bf[(fn * 4 + fk) * 64 + lane], acc1[fn], 0, 0, 0);

        float bv[8], gv[8], bbv[8];
#pragma unroll
        for (int fn = 0; fn < 8; ++fn) {
            bv[fn] = msg_b1[fn * 16 + cn]; gv[fn] = m1g[fn * 16 + cn]; bbv[fn] = m1b[fn * 16 + cn];
        }
#pragma unroll
        for (int reg = 0; reg < 4; ++reg) {
            float val[8];
            float sum = 0.f, sq = 0.f;
#pragma unroll
            for (int fn = 0; fn < 8; ++fn) {
                float v = acc1[fn][reg] + bv[fn];
                v = v * sigf(v);
                val[fn] = v; sum += v; sq += v * v;
            }
#pragma unroll
            for (int m = 1; m < 16; m <<= 1) { sum += __shfl_xor(sum, m); sq += __shfl_xor(sq, m); }
            const float mean = sum * (1.f / 128.f);
            const float var = sq * (1.f / 128.f) - mean * mean;
            const float rstd = rsqrtf(var + LN_EPS);
            const int row16 = rq * 4 + reg;
            const int sw = (row16 & 7) << 3;
#pragma unroll
            for (int fn = 0; fn < 8; ++fn) {
                const float o = (val[fn] - mean) * rstd * gv[fn] + bbv[fn];
                hwB[row16 * 128 + ((fn * 16 + cn) ^ sw)] = f2bf(o);
            }
        }
    }

    // ---- stage 3: xm = m1 @ msg_w2 + msg_b2 ----
    short8 am[4];
    {
        const int row16 = lane & 15;
        const int sw = (row16 & 7) << 3;
#pragma unroll
        for (int fk = 0; fk < 4; ++fk)
            am[fk] = *(const short8*)(hwB + row16 * 128 + ((fk * 32 + kh) ^ sw));
    }
    {
        const short8* Bf = (const short8*)WpM2;
        f32x4 acc2[8];
#pragma unroll
        for (int fn = 0; fn < 8; ++fn) acc2[fn] = (f32x4){0.f, 0.f, 0.f, 0.f};
#pragma unroll
        for (int fk = 0; fk < 4; ++fk)
#pragma unroll
            for (int fn = 0; fn < 8; ++fn)
                acc2[fn] = __builtin_amdgcn_mfma_f32_16x16x32_bf16(am[fk], Bf[(fn * 4 + fk) * 64 + lane], acc2[fn], 0, 0, 0);

        float bv[8];
#pragma unroll
        for (int fn = 0; fn < 8; ++fn) bv[fn] = msg_b2[fn * 16 + cn];
#pragma unroll
        for (int reg = 0; reg < 4; ++reg) {
            const int gr = r0 + w * 16 + rq * 4 + reg;
            if (gr < nrows) {
#pragma unroll
                for (int fn = 0; fn < 8; ++fn)
                    xmH[(size_t)gr * 128 + fn * 16 + cn] = f2bf(acc2[fn][reg] + bv[fn]);
            }
        }
    }
}

// ---- fused double GEMM (out-chain): C = LN(res + LN(silu(A@W1+b1))@W2 + b2) ----
__global__ __launch_bounds__(256, 4)
void gemm2_mfma(const unsigned short* __restrict__ Av,
                const unsigned short* __restrict__ Wp1, const float* __restrict__ b1,
                const float* __restrict__ ln1g, const float* __restrict__ ln1b,
                const unsigned short* __restrict__ Wp2, const float* __restrict__ b2,
                const float* __restrict__ ln2g, const float* __restrict__ ln2b,
                const unsigned short* __restrict__ resH, float* __restrict__ Cf, int nrows)
{
    __shared__ unsigned short hof[4 * 2048];
    const int tid = threadIdx.x;
    const int w = tid >> 6, lane = tid & 63;
    const int r0 = blockIdx.x * 64;
    const int arow = r0 + w * 16 + (lane & 15);
    const size_t rowc = (arow < nrows) ? (size_t)arow : (size_t)(nrows - 1);
    const int kh = (lane >> 4) * 8;
    const int cn = lane & 15, rq = lane >> 4;

    short8 a[4];
#pragma unroll
    for (int fk = 0; fk < 4; ++fk) a[fk] = ldA_bf(Av, rowc, fk * 32 + kh);

    const short8* B1f = (const short8*)Wp1;
    f32x4 acc[8];
#pragma unroll
    for (int fn = 0; fn < 8; ++fn) acc[fn] = (f32x4){0.f, 0.f, 0.f, 0.f};
#pragma unroll
    for (int fk = 0; fk < 4; ++fk)
#pragma unroll
        for (int fn = 0; fn < 8; ++fn)
            acc[fn] = __builtin_amdgcn_mfma_f32_16x16x32_bf16(a[fk], B1f[(fn * 4 + fk) * 64 + lane], acc[fn], 0, 0, 0);

    unsigned short* hw = hof + w * 2048;
    {
        float bv[8], gv[8], bbv[8];
#pragma unroll
        for (int fn = 0; fn < 8; ++fn) {
            bv[fn] = b1[fn * 16 + cn]; gv[fn] = ln1g[fn * 16 + cn]; bbv[fn] = ln1b[fn * 16 + cn];
        }
#pragma unroll
        for (int reg = 0; reg < 4; ++reg) {
            float val[8];
            float sum = 0.f, sq = 0.f;
#pragma unroll
            for (int fn = 0; fn < 8; ++fn) {
                float v = acc[fn][reg] + bv[fn];
                v = v * sigf(v);
                val[fn] = v; sum += v; sq += v * v;
            }
#pragma unroll
            for (int m = 1; m < 16; m <<= 1) { sum += __shfl_xor(sum, m); sq += __shfl_xor(sq, m); }
            const float mean = sum * (1.f / 128.f);
            const float var = sq * (1.f / 128.f) - mean * mean;
            const float rstd = rsqrtf(var + LN_EPS);
            const int row16 = rq * 4 + reg;
            const int sw = (row16 & 7) << 3;
#pragma unroll
            for (int fn = 0; fn < 8; ++fn) {
                const float o = (val[fn] - mean) * rstd * gv[fn] + bbv[fn];
                hw[row16 * 128 + ((fn * 16 + cn) ^ sw)] = f2bf(o);
            }
        }
    }

    short8 a2[4];
    {
        const int row16 = lane & 15;
        const int sw = (row16 & 7) << 3;
#pragma unroll
        for (int fk = 0; fk < 4; ++fk)
            a2[fk] = *(const short8*)(hw + row16 * 128 + ((fk * 32 + kh) ^ sw));
    }

    const short8* B2f = (const short8*)Wp2;
    f32x4 acc2[8];
#pragma unroll
    for (int fn = 0; fn < 8; ++fn) acc2[fn] = (f32x4){0.f, 0.f, 0.f, 0.f};
#pragma unroll
    for (int fk = 0; fk < 4; ++fk)
#pragma unroll
        for (int fn = 0; fn < 8; ++fn)
            acc2[fn] = __builtin_amdgcn_mfma_f32_16x16x32_bf16(a2[fk], B2f[(fn * 4 + fk) * 64 + lane], acc2[fn], 0, 0, 0);

    float bv2[8], gv[8], bbv[8];
#pragma unroll
    for (int fn = 0; fn < 8; ++fn) {
        bv2[fn] = b2[fn * 16 + cn]; gv[fn] = ln2g[fn * 16 + cn]; bbv[fn] = ln2b[fn * 16 + cn];
    }
#pragma unroll
    for (int reg = 0; reg < 4; ++reg) {
        const int gr = r0 + w * 16 + rq * 4 + reg;
        const int grc = gr < nrows ? gr : nrows - 1;
        float val[8];
        float sum = 0.f, sq = 0.f;
#pragma unroll
        for (int fn = 0; fn < 8; ++fn) {
            float v = acc2[fn][reg] + bv2[fn] + bf1f(resH[(size_t)grc * 128 + fn * 16 + cn]);
            val[fn] = v; sum += v; sq += v * v;
        }
#pragma unroll
        for (int m = 1; m < 16; m <<= 1) { sum += __shfl_xor(sum, m); sq += __shfl_xor(sq, m); }
        const float mean = sum * (1.f / 128.f);
        const float var = sq * (1.f / 128.f) - mean * mean;
        const float rstd = rsqrtf(var + LN_EPS);
        if (gr < nrows) {
#pragma unroll
            for (int fn = 0; fn < 8; ++fn)
                Cf[(size_t)gr * 128 + fn * 16 + cn] = (val[fn] - mean) * rstd * gv[fn] + bbv[fn];
        }
    }
}

// ---- histogram + per-edge rank in ONE atomic pass (8-deep ILP) ----
__global__ __launch_bounds__(256)
void hist_rank(const int* __restrict__ row, int* __restrict__ cnt,
               int* __restrict__ rank, int E)
{
    const int tid = blockIdx.x * blockDim.x + threadIdx.x;
    const int stride = gridDim.x * blockDim.x;
    for (int e0 = tid; e0 < E; e0 += stride * 8) {
        int r[8]; bool val[8];
#pragma unroll
        for (int u = 0; u < 8; ++u) {
            const int e = e0 + u * stride;
            val[u] = e < E;
            r[u] = val[u] ? row[e] : 0;
        }
        int rk[8];
#pragma unroll
        for (int u = 0; u < 8; ++u)
            if (val[u]) rk[u] = atomicAdd(&cnt[r[u]], 1);
#pragma unroll
        for (int u = 0; u < 8; ++u)
            if (val[u]) rank[e0 + u * stride] = rk[u];
    }
}

__global__ __launch_bounds__(1024)
void scan_a(const int* __restrict__ cnt, int* __restrict__ off,
            int* __restrict__ btot, int n)
{
    __shared__ int wsum[16];
    const int tid = threadIdx.x, lane = tid & 63, wv = tid >> 6;
    const int i = blockIdx.x * 1024 + tid;
    const int v = (i < n) ? cnt[i] : 0;
    int incl = v;
#pragma unroll
    for (int d = 1; d < 64; d <<= 1) { int t = __shfl_up(incl, d); if (lane >= d) incl += t; }
    if (lane == 63) wsum[wv] = incl;
    __syncthreads();
    if (tid == 0) {
        int run = 0;
        for (int ww = 0; ww < 16; ++ww) { int t = wsum[ww]; wsum[ww] = run; run += t; }
    }
    __syncthreads();
    if (i < n) off[i] = wsum[wv] + incl - v;
    if (tid == 1023) btot[blockIdx.x] = wsum[15] + incl;
}

__global__ __launch_bounds__(64)
void scan_b(int* __restrict__ btot, int* __restrict__ bexc,
            int* __restrict__ off, int n, int nb, int E)
{
    const int t = threadIdx.x;
    const int v = (t < nb) ? btot[t] : 0;
    int incl = v;
#pragma unroll
    for (int d = 1; d < 64; d <<= 1) { int u = __shfl_up(incl, d); if (t >= d) incl += u; }
    if (t < nb) bexc[t] = incl - v;
    if (t == 0) off[n] = E;
}

__global__ __launch_bounds__(1024)
void scan_c(int* __restrict__ off, const int* __restrict__ bexc, int n)
{
    const int i = blockIdx.x * 1024 + threadIdx.x;
    if (i < n) off[i] += bexc[blockIdx.x];
}

// ---- edge-parallel attention, quad-per-edge, original order, fused scatter ----
__global__ __launch_bounds__(256, 4)
void att_edge(const unsigned short* __restrict__ xrH,
              const unsigned short* __restrict__ xcH,
              const int* __restrict__ row, const int* __restrict__ col,
              const float* __restrict__ ea, const float* __restrict__ em,
              const int* __restrict__ rank, const int* __restrict__ off,
              const float* __restrict__ we_, const float* __restrict__ w2_,
              const float* __restrict__ b2p, uint2* __restrict__ catS, int E)
{
    const int lane = threadIdx.x & 63;
    const int q = lane & 3;
    const int gwid = (blockIdx.x * blockDim.x + threadIdx.x) >> 6;
    const int nw = (gridDim.x * blockDim.x) >> 6;

    float we[32], w2[32];
#pragma unroll
    for (int ch = 0; ch < 4; ++ch) {
        const float4 a0 = ((const float4*)we_)[ch * 8 + q * 2];
        const float4 a1 = ((const float4*)we_)[ch * 8 + q * 2 + 1];
        we[ch * 8 + 0] = a0.x; we[ch * 8 + 1] = a0.y; we[ch * 8 + 2] = a0.z; we[ch * 8 + 3] = a0.w;
        we[ch * 8 + 4] = a1.x; we[ch * 8 + 5] = a1.y; we[ch * 8 + 6] = a1.z; we[ch * 8 + 7] = a1.w;
        const float4 c0 = ((const float4*)w2_)[ch * 8 + q * 2];
        const float4 c1 = ((const float4*)w2_)[ch * 8 + q * 2 + 1];
        w2[ch * 8 + 0] = c0.x; w2[ch * 8 + 1] = c0.y; w2[ch * 8 + 2] = c0.z; w2[ch * 8 + 3] = c0.w;
        w2[ch * 8 + 4] = c1.x; w2[ch * 8 + 5] = c1.y; w2[ch * 8 + 6] = c1.z; w2[ch * 8 + 7] = c1.w;
    }
    const float b2 = *b2p;

    for (int base = gwid * 16; base < E; base += nw * 16) {
        const int e = base + (lane >> 2);
        const bool valid = e < E;
        const int ec = valid ? e : E - 1;
        const int r = row[ec], c = col[ec];
        const float eax = ea[ec], emv = em[ec];
        const unsigned short* xr = xrH + (size_t)r * 128;
        const unsigned short* xc = xcH + (size_t)c * 128;
        // 4 independent partial sums -- break the 32-long serial p-chain
        float pc[4];
#pragma unroll
        for (int ch = 0; ch < 4; ++ch) {
            const uint4 pa = *(const uint4*)(xr + ch * 32 + q * 8);
            const uint4 pb = *(const uint4*)(xc + ch * 32 + q * 8);
            float xa[8], xb[8];
            bf8f(pa, xa); bf8f(pb, xb);
            float s = 0.f;
#pragma unroll
            for (int i = 0; i < 8; ++i) {
                const float t = xa[i] + xb[i] + eax * we[ch * 8 + i];
                s += t * sigf(t) * w2[ch * 8 + i];
            }
            pc[ch] = s;
        }
        float p = (pc[0] + pc[1]) + (pc[2] + pc[3]);
        p = quad_add_all(p);
        const float att = sigf(p + b2) * emv;
        if (valid && q == 0) {
            const int pos = off[r] + rank[ec];
            catS[pos] = make_uint2((unsigned)c, __float_as_uint(att));
        }
    }
}

// ---- row accumulation: msgH[r] = bf16( sum att * xm[col] ) ----
__global__ __launch_bounds__(256)
void accum_k(const unsigned short* __restrict__ xmH, const int* __restrict__ off,
             const uint2* __restrict__ catS, unsigned short* __restrict__ msgH, int N)
{
    const int lane = threadIdx.x & 63;
    const int g = lane >> 4, l = lane & 15;
    const int gwid = (blockIdx.x * blockDim.x + threadIdx.x) >> 6;
    const int nw = (gridDim.x * blockDim.x) >> 6;
    const uint4* xm4 = (const uint4*)xmH;

    for (int wid = gwid; wid < N; wid += nw) {
        int j0 = off[wid];
        const int jend = off[wid + 1];
        float acc[8] = {0.f, 0.f, 0.f, 0.f, 0.f, 0.f, 0.f, 0.f};

        for (; j0 + 16 <= jend; j0 += 16) {
            uint2 ca[4]; uint4 pk[4];
#pragma unroll
            for (int u = 0; u < 4; ++u) ca[u] = catS[j0 + u * 4 + g];
#pragma unroll
            for (int u = 0; u < 4; ++u) pk[u] = xm4[(size_t)ca[u].x * 16 + l];
#pragma unroll
            for (int u = 0; u < 4; ++u) {
                const float att = __uint_as_float(ca[u].y);
                float xm[8];
                bf8f(pk[u], xm);
#pragma unroll
                for (int i = 0; i < 8; ++i) acc[i] = fmaf(att, xm[i], acc[i]);
            }
        }
        for (; j0 + 8 <= jend; j0 += 8) {
            const uint2 caA = catS[j0 + g];
            const uint2 caB = catS[j0 + 4 + g];
            const uint4 pA = xm4[(size_t)caA.x * 16 + l];
            const uint4 pB = xm4[(size_t)caB.x * 16 + l];
            const float attA = __uint_as_float(caA.y);
            const float attB = __uint_as_float(caB.y);
            float xmA[8], xmB[8];
            bf8f(pA, xmA); bf8f(pB, xmB);
#pragma unroll
            for (int i = 0; i < 8; ++i)
                acc[i] = fmaf(attB, xmB[i], fmaf(attA, xmA[i], acc[i]));
        }
        for (; j0 < jend; j0 += 4) {
            const int je = j0 + g;
            const bool valid = je < jend;
            const int jc = valid ? je : jend - 1;
            const uint2 ca = catS[jc];
            const uint4 p = xm4[(size_t)ca.x * 16 + l];
            const float att = valid ? __uint_as_float(ca.y) : 0.f;
            float xm[8];
            bf8f(p, xm);
#pragma unroll
            for (int i = 0; i < 8; ++i) acc[i] = fmaf(att, xm[i], acc[i]);
        }

#pragma unroll
        for (int i = 0; i < 8; ++i) {
            acc[i] += __shfl_xor(acc[i], 16);
            acc[i] += __shfl_xor(acc[i], 32);
        }
        if (g == 0) {
            uint4 pk;
            pk.x = f2bf2(acc[0], acc[1]); pk.y = f2bf2(acc[2], acc[3]);
            pk.z = f2bf2(acc[4], acc[5]); pk.w = f2bf2(acc[6], acc[7]);
            ((uint4*)msgH)[(size_t)wid * 16 + l] = pk;
        }
    }
}

extern "C" void kernel_launch(void* const* d_in, const int* in_sizes, int n_in,
                              void* d_out, int out_size, void* d_ws, size_t ws_size,
                              hipStream_t stream)
{
    const float* h        = (const float*)d_in[0];
    const float* edge_attr= (const float*)d_in[1];
    const int*   row      = (const int*)d_in[2];
    const int*   col      = (const int*)d_in[3];
    const float* edge_mask= (const float*)d_in[5];
    const float* lin_w    = (const float*)d_in[6];
    const float* lin_b    = (const float*)d_in[7];
    const float* msg_w1   = (const float*)d_in[8];
    const float* msg_b1   = (const float*)d_in[9];
    const float* msg_ln_g = (const float*)d_in[10];
    const float* msg_ln_b = (const float*)d_in[11];
    const float* msg_w2   = (const float*)d_in[12];
    const float* msg_b2   = (const float*)d_in[13];
    const float* att_w1   = (const float*)d_in[14];
    const float* att_b1   = (const float*)d_in[15];
    const float* att_w2   = (const float*)d_in[16];
    const float* att_b2   = (const float*)d_in[17];
    const float* out_w1   = (const float*)d_in[18];
    const float* out_b1   = (const float*)d_in[19];
    const float* out_ln_g = (const float*)d_in[20];
    const float* out_ln_b = (const float*)d_in[21];
    const float* out_w2   = (const float*)d_in[22];
    const float* out_b2   = (const float*)d_in[23];
    const float* ln_g     = (const float*)d_in[24];
    const float* ln_b     = (const float*)d_in[25];

    const int N = in_sizes[0] / 128;
    const int E = in_sizes[2];
    const size_t NF = (size_t)N * 128;

    unsigned short* xbH  = (unsigned short*)d_ws;       // bf16 [N][128] x
    unsigned short* xrH  = xbH + NF;                    // bf16 [N][128]
    unsigned short* xcH  = xrH + NF;                    // bf16 [N][128]
    unsigned short* xmH  = xcH + NF;                    // bf16 [N][128]
    unsigned short* msgH = xmH + NF;                    // bf16 [N][128]
    int*    cnt   = (int*)(msgH + NF);                  // N
    int*    off   = cnt + N;                            // N+1 (alloc N+8)
    int*    btot  = off + N + 8;                        // 64
    int*    bexc  = btot + 64;                          // 64
    int*    rank  = bexc + 64;                          // E
    uint2*  catS  = (uint2*)(rank + E);                 // E
    unsigned short* wp = (unsigned short*)(catS + E);   // 8*16384 bf16
    float* bias256 = (float*)(wp + 8 * 16384);

    const int gb = (N + 63) / 64;
    const int nb = (N + 1023) / 1024;
    const int hgrid = (E + 256 * 8 - 1) / (256 * 8);    // ~8 edges/thread

    prep_w<<<513, 256, 0, stream>>>(lin_w, msg_w1, msg_w2, att_w1, out_w1, out_w2,
                                    att_b1, wp, bias256);
    hipMemsetAsync(cnt, 0, (size_t)N * sizeof(int), stream);
    hist_rank<<<hgrid, 256, 0, stream>>>(row, cnt, rank, E);
    scan_a<<<nb, 1024, 0, stream>>>(cnt, off, btot, N);
    scan_b<<<1, 64, 0, stream>>>(btot, bexc, off, N, nb, E);
    scan_c<<<nb, 1024, 0, stream>>>(off, bexc, N);

    // fused front: lin -> {att-proj, msg1 -> msg2}
    front_mfma<<<gb, 256, 0, stream>>>(h, wp, lin_b,
                                       wp + 3 * 16384, bias256,
                                       wp + 16384, msg_b1, msg_ln_g, msg_ln_b,
                                       wp + 2 * 16384, msg_b2,
                                       xbH, xrH, xcH, xmH, N);

    // att scalars, original edge order, fused scatter into sorted catS
    att_edge<<<2048, 256, 0, stream>>>(xrH, xcH, row, col, edge_attr, edge_mask,
                                       rank, off, att_w1 + 256 * 128, att_w2, att_b2,
                                       catS, E);

    // msg[r] = sum att * xm[col]  (bf16 out)
    accum_k<<<2048, 256, 0, stream>>>(xmH, off, catS, msgH, N);

    // out = LN(x + (LN(silu(msg @ out_w1 + out_b1))) @ out_w2 + out_b2)
    gemm2_mfma<<<gb, 256, 0, stream>>>(msgH, wp + 5 * 16384, out_b1, out_ln_g, out_ln_b,
                                       wp + 6 * 16384, out_b2, ln_g, ln_b,
                                       xbH, (float*)d_out, N);
}

// Round 12
// 201.927 us; speedup vs baseline: 1.5770x; 1.1435x over previous
//
#include <hip/hip_runtime.h>

#define LN_EPS 1e-5f

typedef __attribute__((ext_vector_type(8))) short short8;
typedef __attribute__((ext_vector_type(4))) float f32x4;

// sigmoid via native exp + rcp (NO IEEE division)
__device__ __forceinline__ float sigf(float x) {
    return __builtin_amdgcn_rcpf(1.0f + __expf(-x));
}

__device__ __forceinline__ unsigned short f2bf(float f) {
    unsigned u = __float_as_uint(f);
    return (unsigned short)((u + 0x7fffu + ((u >> 16) & 1u)) >> 16);
}
__device__ __forceinline__ unsigned f2bf2(float lo, float hi) {
    return (unsigned)f2bf(lo) | ((unsigned)f2bf(hi) << 16);
}
__device__ __forceinline__ void bf2f(unsigned u, float& lo, float& hi) {
    lo = __uint_as_float(u << 16);
    hi = __uint_as_float(u & 0xffff0000u);
}
__device__ __forceinline__ void bf8f(uint4 p, float* o) {
    bf2f(p.x, o[0], o[1]); bf2f(p.y, o[2], o[3]);
    bf2f(p.z, o[4], o[5]); bf2f(p.w, o[6], o[7]);
}
__device__ __forceinline__ float bf1f(unsigned short s) {
    return __uint_as_float(((unsigned)s) << 16);
}

// butterfly sum over each quad via DPP quad_perm — no DS ops
__device__ __forceinline__ float quad_add_all(float x) {
    int v = __builtin_amdgcn_update_dpp(0, __float_as_int(x), 0xB1, 0xF, 0xF, true);
    x += __int_as_float(v);
    v = __builtin_amdgcn_update_dpp(0, __float_as_int(x), 0x4E, 0xF, 0xF, true);
    x += __int_as_float(v);
    return x;
}

// ---- weight prep: f32 [128][128] row-major -> fragment-linear bf16 ----
__global__ __launch_bounds__(256)
void prep_w(const float* __restrict__ lin_w, const float* __restrict__ msg_w1,
            const float* __restrict__ msg_w2, const float* __restrict__ att_w1,
            const float* __restrict__ out_w1, const float* __restrict__ out_w2,
            const float* __restrict__ att_b1, unsigned short* __restrict__ wp,
            float* __restrict__ bias256)
{
    const int idx = blockIdx.x * 256 + threadIdx.x;
    if (idx < 8 * 16384) {
        const int m = idx >> 14, r = idx & 16383;
        const int k = r >> 7, n = r & 127;
        const float* src; int slot; int fnBase = 0;
        switch (m) {
            case 0: src = lin_w;  slot = 0; break;
            case 1: src = msg_w1; slot = 1; break;
            case 2: src = msg_w2; slot = 2; break;
            case 3: src = att_w1; slot = 3; break;
            case 4: src = att_w1 + 128 * 128; slot = 3; fnBase = 8; break;
            case 5: src = out_w1; slot = 5; break;
            default: src = out_w2; slot = 6; break;
        }
        const float v = src[k * 128 + n];
        const int fn = fnBase + (n >> 4);
        const int fk = k >> 5, kb = (k >> 3) & 3, j = k & 7;
        const size_t dst = (size_t)slot * 16384 + ((size_t)((fn * 4 + fk) * 64 + (n & 15) + 16 * kb)) * 8 + j;
        wp[dst] = f2bf(v);
    } else if (idx < 8 * 16384 + 256) {
        const int t = idx - 8 * 16384;
        bias256[t] = (t < 128) ? att_b1[t] : 0.f;
    }
}

__device__ __forceinline__ short8 ldA_f32(const float* A, size_t row, int k0) {
    const float* ap = A + row * 128 + k0;
    const float4 f0 = *(const float4*)ap;
    const float4 f1 = *(const float4*)(ap + 4);
    union { unsigned u[4]; short8 s; } v;
    v.u[0] = f2bf2(f0.x, f0.y); v.u[1] = f2bf2(f0.z, f0.w);
    v.u[2] = f2bf2(f1.x, f1.y); v.u[3] = f2bf2(f1.z, f1.w);
    return v.s;
}
__device__ __forceinline__ short8 ldA_bf(const unsigned short* A, size_t row, int k0) {
    return *(const short8*)(A + row * 128 + k0);
}

// ---- fused FRONT kernel v2: block-staged B in LDS, coalesced outputs ----
// 5 B-stages: lin, att_r, att_c, msg1, msg2. Bbuf barrier-bracketed;
// hof is wave-private (4 KiB/wave), time-multiplexed, same-wave ordered.
__global__ __launch_bounds__(256, 3)
void front_mfma(const float* __restrict__ h,
                const unsigned short* __restrict__ wp, const float* __restrict__ lin_b,
                const float* __restrict__ att_b1,
                const float* __restrict__ msg_b1,
                const float* __restrict__ m1g, const float* __restrict__ m1b,
                const float* __restrict__ msg_b2,
                unsigned short* __restrict__ xbH, unsigned short* __restrict__ xrH,
                unsigned short* __restrict__ xcH, unsigned short* __restrict__ xmH,
                int nrows)
{
    __shared__ uint4 Bbuf[2048];                // 32 KiB: one 128x128 bf16 frag-linear W
    __shared__ unsigned short hof[4 * 2048];    // 16 KiB: 4 KiB per wave
    const int tid = threadIdx.x;
    const int w = tid >> 6, lane = tid & 63;
    const int r0 = blockIdx.x * 64;
    const int arow = r0 + w * 16 + (lane & 15);
    const size_t rowc = (arow < nrows) ? (size_t)arow : (size_t)(nrows - 1);
    const int kh = (lane >> 4) * 8;
    const int cn = lane & 15, rq = lane >> 4;
    unsigned short* hw = hof + w * 2048;
    const short8* Bf = (const short8*)Bbuf;

    // ---- A-load for stage 0 (overlaps first B staging) ----
    short8 a[4];
#pragma unroll
    for (int fk = 0; fk < 4; ++fk) a[fk] = ldA_f32(h, rowc, fk * 32 + kh);

    // B stage helper (256 threads x 8 uint4 = 2048)
    const uint4* wp4 = (const uint4*)wp;

#define LOADB(slotoff)  { _Pragma("unroll") \
    for (int i = 0; i < 8; ++i) Bbuf[tid + i * 256] = wp4[(slotoff) + tid + i * 256]; }

#define MFMA8(afrag, accv) { _Pragma("unroll") \
    for (int fk = 0; fk < 4; ++fk) { _Pragma("unroll") \
        for (int fn = 0; fn < 8; ++fn) \
            accv[fn] = __builtin_amdgcn_mfma_f32_16x16x32_bf16(afrag[fk], Bf[(fn * 4 + fk) * 64 + lane], accv[fn], 0, 0, 0); } }

    // epi -> hof (swizzled), bias only
#define EPI_HOF(accv, bvv) { _Pragma("unroll") \
    for (int reg = 0; reg < 4; ++reg) { \
        const int row16 = rq * 4 + reg; const int sw = (row16 & 7) << 3; _Pragma("unroll") \
        for (int fn = 0; fn < 8; ++fn) \
            hw[row16 * 128 + ((fn * 16 + cn) ^ sw)] = f2bf(accv[fn][reg] + bvv[fn]); } }

    // flush wave tile hof -> G coalesced (4 x 16B per lane)
#define FLUSH(G) { const int frow = lane >> 2; const int fgr = r0 + w * 16 + frow; \
    const int fsw = (frow & 7) << 3; _Pragma("unroll") \
    for (int it = 0; it < 4; ++it) { \
        const int c0 = ((lane & 3) + it * 4) * 8; \
        short8 v = *(const short8*)(hw + frow * 128 + (c0 ^ fsw)); \
        if (fgr < nrows) *(short8*)((G) + (size_t)fgr * 128 + c0) = v; } }

    // ---- stage 0: x = h @ lin_w + lin_b ----
    LOADB(0);
    __syncthreads();
    f32x4 acc[8];
#pragma unroll
    for (int fn = 0; fn < 8; ++fn) acc[fn] = (f32x4){0.f, 0.f, 0.f, 0.f};
    MFMA8(a, acc);
    {
        float bv[8];
#pragma unroll
        for (int fn = 0; fn < 8; ++fn) bv[fn] = lin_b[fn * 16 + cn];
        EPI_HOF(acc, bv);
    }
    // x as A-frags from hof
    short8 ax[4];
    {
        const int row16 = lane & 15;
        const int sw = (row16 & 7) << 3;
#pragma unroll
        for (int fk = 0; fk < 4; ++fk)
            ax[fk] = *(const short8*)(hw + row16 * 128 + ((fk * 32 + kh) ^ sw));
    }
    FLUSH(xbH);
    __syncthreads();

    // ---- stage 1: xr = x @ att_w1[:128] + att_b1 ----
    LOADB(3 * 2048);
    __syncthreads();
#pragma unroll
    for (int fn = 0; fn < 8; ++fn) acc[fn] = (f32x4){0.f, 0.f, 0.f, 0.f};
    MFMA8(ax, acc);
    {
        float bv[8];
#pragma unroll
        for (int fn = 0; fn < 8; ++fn) bv[fn] = att_b1[fn * 16 + cn];
        EPI_HOF(acc, bv);
    }
    FLUSH(xrH);
    __syncthreads();

    // ---- stage 2: xc = x @ att_w1[128:256] ----
    LOADB(4 * 2048);
    __syncthreads();
#pragma unroll
    for (int fn = 0; fn < 8; ++fn) acc[fn] = (f32x4){0.f, 0.f, 0.f, 0.f};
    MFMA8(ax, acc);
    {
        float bv[8];
#pragma unroll
        for (int fn = 0; fn < 8; ++fn) bv[fn] = 0.f;
        EPI_HOF(acc, bv);
    }
    FLUSH(xcH);
    __syncthreads();

    // ---- stage 3: m1 = LN(silu(x @ msg_w1 + msg_b1)) -> hof ----
    LOADB(1 * 2048);
    __syncthreads();
#pragma unroll
    for (int fn = 0; fn < 8; ++fn) acc[fn] = (f32x4){0.f, 0.f, 0.f, 0.f};
    MFMA8(ax, acc);
    {
        float bv[8], gv[8], bbv[8];
#pragma unroll
        for (int fn = 0; fn < 8; ++fn) {
            bv[fn] = msg_b1[fn * 16 + cn]; gv[fn] = m1g[fn * 16 + cn]; bbv[fn] = m1b[fn * 16 + cn];
        }
#pragma unroll
        for (int reg = 0; reg < 4; ++reg) {
            float val[8];
            float sum = 0.f, sq = 0.f;
#pragma unroll
            for (int fn = 0; fn < 8; ++fn) {
                float v = acc[fn][reg] + bv[fn];
                v = v * sigf(v);
                val[fn] = v; sum += v; sq += v * v;
            }
#pragma unroll
            for (int m = 1; m < 16; m <<= 1) { sum += __shfl_xor(sum, m); sq += __shfl_xor(sq, m); }
            const float mean = sum * (1.f / 128.f);
            const float var = sq * (1.f / 128.f) - mean * mean;
            const float rstd = rsqrtf(var + LN_EPS);
            const int row16 = rq * 4 + reg;
            const int sw = (row16 & 7) << 3;
#pragma unroll
            for (int fn = 0; fn < 8; ++fn) {
                const float o = (val[fn] - mean) * rstd * gv[fn] + bbv[fn];
                hw[row16 * 128 + ((fn * 16 + cn) ^ sw)] = f2bf(o);
            }
        }
    }
    short8 am[4];
    {
        const int row16 = lane & 15;
        const int sw = (row16 & 7) << 3;
#pragma unroll
        for (int fk = 0; fk < 4; ++fk)
            am[fk] = *(const short8*)(hw + row16 * 128 + ((fk * 32 + kh) ^ sw));
    }
    __syncthreads();

    // ---- stage 4: xm = m1 @ msg_w2 + msg_b2 ----
    LOADB(2 * 2048);
    __syncthreads();
#pragma unroll
    for (int fn = 0; fn < 8; ++fn) acc[fn] = (f32x4){0.f, 0.f, 0.f, 0.f};
    MFMA8(am, acc);
    {
        float bv[8];
#pragma unroll
        for (int fn = 0; fn < 8; ++fn) bv[fn] = msg_b2[fn * 16 + cn];
        EPI_HOF(acc, bv);
    }
    FLUSH(xmH);
#undef LOADB
#undef MFMA8
#undef EPI_HOF
#undef FLUSH
}

// ---- fused double GEMM (out-chain): C = LN(res + LN(silu(A@W1+b1))@W2 + b2) ----
__global__ __launch_bounds__(256, 4)
void gemm2_mfma(const unsigned short* __restrict__ Av,
                const unsigned short* __restrict__ Wp1, const float* __restrict__ b1,
                const float* __restrict__ ln1g, const float* __restrict__ ln1b,
                const unsigned short* __restrict__ Wp2, const float* __restrict__ b2,
                const float* __restrict__ ln2g, const float* __restrict__ ln2b,
                const unsigned short* __restrict__ resH, float* __restrict__ Cf, int nrows)
{
    __shared__ unsigned short hof[4 * 2048];
    const int tid = threadIdx.x;
    const int w = tid >> 6, lane = tid & 63;
    const int r0 = blockIdx.x * 64;
    const int arow = r0 + w * 16 + (lane & 15);
    const size_t rowc = (arow < nrows) ? (size_t)arow : (size_t)(nrows - 1);
    const int kh = (lane >> 4) * 8;
    const int cn = lane & 15, rq = lane >> 4;

    short8 a[4];
#pragma unroll
    for (int fk = 0; fk < 4; ++fk) a[fk] = ldA_bf(Av, rowc, fk * 32 + kh);

    const short8* B1f = (const short8*)Wp1;
    f32x4 acc[8];
#pragma unroll
    for (int fn = 0; fn < 8; ++fn) acc[fn] = (f32x4){0.f, 0.f, 0.f, 0.f};
#pragma unroll
    for (int fk = 0; fk < 4; ++fk)
#pragma unroll
        for (int fn = 0; fn < 8; ++fn)
            acc[fn] = __builtin_amdgcn_mfma_f32_16x16x32_bf16(a[fk], B1f[(fn * 4 + fk) * 64 + lane], acc[fn], 0, 0, 0);

    unsigned short* hw = hof + w * 2048;
    {
        float bv[8], gv[8], bbv[8];
#pragma unroll
        for (int fn = 0; fn < 8; ++fn) {
            bv[fn] = b1[fn * 16 + cn]; gv[fn] = ln1g[fn * 16 + cn]; bbv[fn] = ln1b[fn * 16 + cn];
        }
#pragma unroll
        for (int reg = 0; reg < 4; ++reg) {
            float val[8];
            float sum = 0.f, sq = 0.f;
#pragma unroll
            for (int fn = 0; fn < 8; ++fn) {
                float v = acc[fn][reg] + bv[fn];
                v = v * sigf(v);
                val[fn] = v; sum += v; sq += v * v;
            }
#pragma unroll
            for (int m = 1; m < 16; m <<= 1) { sum += __shfl_xor(sum, m); sq += __shfl_xor(sq, m); }
            const float mean = sum * (1.f / 128.f);
            const float var = sq * (1.f / 128.f) - mean * mean;
            const float rstd = rsqrtf(var + LN_EPS);
            const int row16 = rq * 4 + reg;
            const int sw = (row16 & 7) << 3;
#pragma unroll
            for (int fn = 0; fn < 8; ++fn) {
                const float o = (val[fn] - mean) * rstd * gv[fn] + bbv[fn];
                hw[row16 * 128 + ((fn * 16 + cn) ^ sw)] = f2bf(o);
            }
        }
    }

    short8 a2[4];
    {
        const int row16 = lane & 15;
        const int sw = (row16 & 7) << 3;
#pragma unroll
        for (int fk = 0; fk < 4; ++fk)
            a2[fk] = *(const short8*)(hw + row16 * 128 + ((fk * 32 + kh) ^ sw));
    }

    const short8* B2f = (const short8*)Wp2;
    f32x4 acc2[8];
#pragma unroll
    for (int fn = 0; fn < 8; ++fn) acc2[fn] = (f32x4){0.f, 0.f, 0.f, 0.f};
#pragma unroll
    for (int fk = 0; fk < 4; ++fk)
#pragma unroll
        for (int fn = 0; fn < 8; ++fn)
            acc2[fn] = __builtin_amdgcn_mfma_f32_16x16x32_bf16(a2[fk], B2f[(fn * 4 + fk) * 64 + lane], acc2[fn], 0, 0, 0);

    float bv2[8], gv[8], bbv[8];
#pragma unroll
    for (int fn = 0; fn < 8; ++fn) {
        bv2[fn] = b2[fn * 16 + cn]; gv[fn] = ln2g[fn * 16 + cn]; bbv[fn] = ln2b[fn * 16 + cn];
    }
#pragma unroll
    for (int reg = 0; reg < 4; ++reg) {
        const int gr = r0 + w * 16 + rq * 4 + reg;
        const int grc = gr < nrows ? gr : nrows - 1;
        float val[8];
        float sum = 0.f, sq = 0.f;
#pragma unroll
        for (int fn = 0; fn < 8; ++fn) {
            float v = acc2[fn][reg] + bv2[fn] + bf1f(resH[(size_t)grc * 128 + fn * 16 + cn]);
            val[fn] = v; sum += v; sq += v * v;
        }
#pragma unroll
        for (int m = 1; m < 16; m <<= 1) { sum += __shfl_xor(sum, m); sq += __shfl_xor(sq, m); }
        const float mean = sum * (1.f / 128.f);
        const float var = sq * (1.f / 128.f) - mean * mean;
        const float rstd = rsqrtf(var + LN_EPS);
        if (gr < nrows) {
#pragma unroll
            for (int fn = 0; fn < 8; ++fn)
                Cf[(size_t)gr * 128 + fn * 16 + cn] = (val[fn] - mean) * rstd * gv[fn] + bbv[fn];
        }
    }
}

// ---- histogram + per-edge rank in ONE atomic pass (8-deep ILP) ----
__global__ __launch_bounds__(256)
void hist_rank(const int* __restrict__ row, int* __restrict__ cnt,
               int* __restrict__ rank, int E)
{
    const int tid = blockIdx.x * blockDim.x + threadIdx.x;
    const int stride = gridDim.x * blockDim.x;
    for (int e0 = tid; e0 < E; e0 += stride * 8) {
        int r[8]; bool val[8];
#pragma unroll
        for (int u = 0; u < 8; ++u) {
            const int e = e0 + u * stride;
            val[u] = e < E;
            r[u] = val[u] ? row[e] : 0;
        }
        int rk[8];
#pragma unroll
        for (int u = 0; u < 8; ++u)
            if (val[u]) rk[u] = atomicAdd(&cnt[r[u]], 1);
#pragma unroll
        for (int u = 0; u < 8; ++u)
            if (val[u]) rank[e0 + u * stride] = rk[u];
    }
}

__global__ __launch_bounds__(1024)
void scan_a(const int* __restrict__ cnt, int* __restrict__ off,
            int* __restrict__ btot, int n)
{
    __shared__ int wsum[16];
    const int tid = threadIdx.x, lane = tid & 63, wv = tid >> 6;
    const int i = blockIdx.x * 1024 + tid;
    const int v = (i < n) ? cnt[i] : 0;
    int incl = v;
#pragma unroll
    for (int d = 1; d < 64; d <<= 1) { int t = __shfl_up(incl, d); if (lane >= d) incl += t; }
    if (lane == 63) wsum[wv] = incl;
    __syncthreads();
    if (tid == 0) {
        int run = 0;
        for (int ww = 0; ww < 16; ++ww) { int t = wsum[ww]; wsum[ww] = run; run += t; }
    }
    __syncthreads();
    if (i < n) off[i] = wsum[wv] + incl - v;
    if (tid == 1023) btot[blockIdx.x] = wsum[15] + incl;
}

__global__ __launch_bounds__(64)
void scan_b(int* __restrict__ btot, int* __restrict__ bexc,
            int* __restrict__ off, int n, int nb, int E)
{
    const int t = threadIdx.x;
    const int v = (t < nb) ? btot[t] : 0;
    int incl = v;
#pragma unroll
    for (int d = 1; d < 64; d <<= 1) { int u = __shfl_up(incl, d); if (t >= d) incl += u; }
    if (t < nb) bexc[t] = incl - v;
    if (t == 0) off[n] = E;
}

__global__ __launch_bounds__(1024)
void scan_c(int* __restrict__ off, const int* __restrict__ bexc, int n)
{
    const int i = blockIdx.x * 1024 + threadIdx.x;
    if (i < n) off[i] += bexc[blockIdx.x];
}

// ---- edge-parallel attention, quad-per-edge, original order, fused scatter ----
__global__ __launch_bounds__(256, 4)
void att_edge(const unsigned short* __restrict__ xrH,
              const unsigned short* __restrict__ xcH,
              const int* __restrict__ row, const int* __restrict__ col,
              const float* __restrict__ ea, const float* __restrict__ em,
              const int* __restrict__ rank, const int* __restrict__ off,
              const float* __restrict__ we_, const float* __restrict__ w2_,
              const float* __restrict__ b2p, uint2* __restrict__ catS, int E)
{
    const int lane = threadIdx.x & 63;
    const int q = lane & 3;
    const int gwid = (blockIdx.x * blockDim.x + threadIdx.x) >> 6;
    const int nw = (gridDim.x * blockDim.x) >> 6;

    float we[32], w2[32];
#pragma unroll
    for (int ch = 0; ch < 4; ++ch) {
        const float4 a0 = ((const float4*)we_)[ch * 8 + q * 2];
        const float4 a1 = ((const float4*)we_)[ch * 8 + q * 2 + 1];
        we[ch * 8 + 0] = a0.x; we[ch * 8 + 1] = a0.y; we[ch * 8 + 2] = a0.z; we[ch * 8 + 3] = a0.w;
        we[ch * 8 + 4] = a1.x; we[ch * 8 + 5] = a1.y; we[ch * 8 + 6] = a1.z; we[ch * 8 + 7] = a1.w;
        const float4 c0 = ((const float4*)w2_)[ch * 8 + q * 2];
        const float4 c1 = ((const float4*)w2_)[ch * 8 + q * 2 + 1];
        w2[ch * 8 + 0] = c0.x; w2[ch * 8 + 1] = c0.y; w2[ch * 8 + 2] = c0.z; w2[ch * 8 + 3] = c0.w;
        w2[ch * 8 + 4] = c1.x; w2[ch * 8 + 5] = c1.y; w2[ch * 8 + 6] = c1.z; w2[ch * 8 + 7] = c1.w;
    }
    const float b2 = *b2p;

    for (int base = gwid * 16; base < E; base += nw * 16) {
        const int e = base + (lane >> 2);
        const bool valid = e < E;
        const int ec = valid ? e : E - 1;
        const int r = row[ec], c = col[ec];
        const float eax = ea[ec], emv = em[ec];
        const unsigned short* xr = xrH + (size_t)r * 128;
        const unsigned short* xc = xcH + (size_t)c * 128;
        float pc[4];
#pragma unroll
        for (int ch = 0; ch < 4; ++ch) {
            const uint4 pa = *(const uint4*)(xr + ch * 32 + q * 8);
            const uint4 pb = *(const uint4*)(xc + ch * 32 + q * 8);
            float xa[8], xb[8];
            bf8f(pa, xa); bf8f(pb, xb);
            float s = 0.f;
#pragma unroll
            for (int i = 0; i < 8; ++i) {
                const float t = xa[i] + xb[i] + eax * we[ch * 8 + i];
                s += t * sigf(t) * w2[ch * 8 + i];
            }
            pc[ch] = s;
        }
        float p = (pc[0] + pc[1]) + (pc[2] + pc[3]);
        p = quad_add_all(p);
        const float att = sigf(p + b2) * emv;
        if (valid && q == 0) {
            const int pos = off[r] + rank[ec];
            catS[pos] = make_uint2((unsigned)c, __float_as_uint(att));
        }
    }
}

// ---- row accumulation: msgH[r] = bf16( sum att * xm[col] ) ----
__global__ __launch_bounds__(256)
void accum_k(const unsigned short* __restrict__ xmH, const int* __restrict__ off,
             const uint2* __restrict__ catS, unsigned short* __restrict__ msgH, int N)
{
    const int lane = threadIdx.x & 63;
    const int g = lane >> 4, l = lane & 15;
    const int gwid = (blockIdx.x * blockDim.x + threadIdx.x) >> 6;
    const int nw = (gridDim.x * blockDim.x) >> 6;
    const uint4* xm4 = (const uint4*)xmH;

    for (int wid = gwid; wid < N; wid += nw) {
        int j0 = off[wid];
        const int jend = off[wid + 1];
        float acc[8] = {0.f, 0.f, 0.f, 0.f, 0.f, 0.f, 0.f, 0.f};

        for (; j0 + 16 <= jend; j0 += 16) {
            uint2 ca[4]; uint4 pk[4];
#pragma unroll
            for (int u = 0; u < 4; ++u) ca[u] = catS[j0 + u * 4 + g];
#pragma unroll
            for (int u = 0; u < 4; ++u) pk[u] = xm4[(size_t)ca[u].x * 16 + l];
#pragma unroll
            for (int u = 0; u < 4; ++u) {
                const float att = __uint_as_float(ca[u].y);
                float xm[8];
                bf8f(pk[u], xm);
#pragma unroll
                for (int i = 0; i < 8; ++i) acc[i] = fmaf(att, xm[i], acc[i]);
            }
        }
        for (; j0 + 8 <= jend; j0 += 8) {
            const uint2 caA = catS[j0 + g];
            const uint2 caB = catS[j0 + 4 + g];
            const uint4 pA = xm4[(size_t)caA.x * 16 + l];
            const uint4 pB = xm4[(size_t)caB.x * 16 + l];
            const float attA = __uint_as_float(caA.y);
            const float attB = __uint_as_float(caB.y);
            float xmA[8], xmB[8];
            bf8f(pA, xmA); bf8f(pB, xmB);
#pragma unroll
            for (int i = 0; i < 8; ++i)
                acc[i] = fmaf(attB, xmB[i], fmaf(attA, xmA[i], acc[i]));
        }
        for (; j0 < jend; j0 += 4) {
            const int je = j0 + g;
            const bool valid = je < jend;
            const int jc = valid ? je : jend - 1;
            const uint2 ca = catS[jc];
            const uint4 p = xm4[(size_t)ca.x * 16 + l];
            const float att = valid ? __uint_as_float(ca.y) : 0.f;
            float xm[8];
            bf8f(p, xm);
#pragma unroll
            for (int i = 0; i < 8; ++i) acc[i] = fmaf(att, xm[i], acc[i]);
        }

#pragma unroll
        for (int i = 0; i < 8; ++i) {
            acc[i] += __shfl_xor(acc[i], 16);
            acc[i] += __shfl_xor(acc[i], 32);
        }
        if (g == 0) {
            uint4 pk;
            pk.x = f2bf2(acc[0], acc[1]); pk.y = f2bf2(acc[2], acc[3]);
            pk.z = f2bf2(acc[4], acc[5]); pk.w = f2bf2(acc[6], acc[7]);
            ((uint4*)msgH)[(size_t)wid * 16 + l] = pk;
        }
    }
}

extern "C" void kernel_launch(void* const* d_in, const int* in_sizes, int n_in,
                              void* d_out, int out_size, void* d_ws, size_t ws_size,
                              hipStream_t stream)
{
    const float* h        = (const float*)d_in[0];
    const float* edge_attr= (const float*)d_in[1];
    const int*   row      = (const int*)d_in[2];
    const int*   col      = (const int*)d_in[3];
    const float* edge_mask= (const float*)d_in[5];
    const float* lin_w    = (const float*)d_in[6];
    const float* lin_b    = (const float*)d_in[7];
    const float* msg_w1   = (const float*)d_in[8];
    const float* msg_b1   = (const float*)d_in[9];
    const float* msg_ln_g = (const float*)d_in[10];
    const float* msg_ln_b = (const float*)d_in[11];
    const float* msg_w2   = (const float*)d_in[12];
    const float* msg_b2   = (const float*)d_in[13];
    const float* att_w1   = (const float*)d_in[14];
    const float* att_b1   = (const float*)d_in[15];
    const float* att_w2   = (const float*)d_in[16];
    const float* att_b2   = (const float*)d_in[17];
    const float* out_w1   = (const float*)d_in[18];
    const float* out_b1   = (const float*)d_in[19];
    const float* out_ln_g = (const float*)d_in[20];
    const float* out_ln_b = (const float*)d_in[21];
    const float* out_w2   = (const float*)d_in[22];
    const float* out_b2   = (const float*)d_in[23];
    const float* ln_g     = (const float*)d_in[24];
    const float* ln_b     = (const float*)d_in[25];

    const int N = in_sizes[0] / 128;
    const int E = in_sizes[2];
    const size_t NF = (size_t)N * 128;

    unsigned short* xbH  = (unsigned short*)d_ws;       // bf16 [N][128] x
    unsigned short* xrH  = xbH + NF;                    // bf16 [N][128]
    unsigned short* xcH  = xrH + NF;                    // bf16 [N][128]
    unsigned short* xmH  = xcH + NF;                    // bf16 [N][128]
    unsigned short* msgH = xmH + NF;                    // bf16 [N][128]
    int*    cnt   = (int*)(msgH + NF);                  // N
    int*    off   = cnt + N;                            // N+1 (alloc N+8)
    int*    btot  = off + N + 8;                        // 64
    int*    bexc  = btot + 64;                          // 64
    int*    rank  = bexc + 64;                          // E
    uint2*  catS  = (uint2*)(rank + E);                 // E
    unsigned short* wp = (unsigned short*)(catS + E);   // 8*16384 bf16
    float* bias256 = (float*)(wp + 8 * 16384);

    const int gb = (N + 63) / 64;
    const int nb = (N + 1023) / 1024;
    const int hgrid = (E + 256 * 8 - 1) / (256 * 8);

    prep_w<<<513, 256, 0, stream>>>(lin_w, msg_w1, msg_w2, att_w1, out_w1, out_w2,
                                    att_b1, wp, bias256);
    hipMemsetAsync(cnt, 0, (size_t)N * sizeof(int), stream);
    hist_rank<<<hgrid, 256, 0, stream>>>(row, cnt, rank, E);
    scan_a<<<nb, 1024, 0, stream>>>(cnt, off, btot, N);
    scan_b<<<1, 64, 0, stream>>>(btot, bexc, off, N, nb, E);
    scan_c<<<nb, 1024, 0, stream>>>(off, bexc, N);

    // fused front v2: lin -> {att_r, att_c, msg1 -> msg2}, LDS-staged B
    front_mfma<<<gb, 256, 0, stream>>>(h, wp, lin_b, att_b1,
                                       msg_b1, msg_ln_g, msg_ln_b, msg_b2,
                                       xbH, xrH, xcH, xmH, N);

    // att scalars, original edge order, fused scatter into sorted catS
    att_edge<<<2048, 256, 0, stream>>>(xrH, xcH, row, col, edge_attr, edge_mask,
                                       rank, off, att_w1 + 256 * 128, att_w2, att_b2,
                                       catS, E);

    // msg[r] = sum att * xm[col]  (bf16 out)
    accum_k<<<2048, 256, 0, stream>>>(xmH, off, catS, msgH, N);

    // out = LN(x + (LN(silu(msg @ out_w1 + out_b1))) @ out_w2 + out_b2)
    gemm2_mfma<<<gb, 256, 0, stream>>>(msgH, wp + 5 * 16384, out_b1, out_ln_g, out_ln_b,
                                       wp + 6 * 16384, out_b2, ln_g, ln_b,
                                       xbH, (float*)d_out, N);
}